// Round 1
// baseline (1646.082 us; speedup 1.0000x reference)
//
#include <hip/hip_runtime.h>
#include <math.h>

#define EMB 1024
#define NH 16
#define HD 64
#define NB 2
#define SQ 2048
#define BSQ (NB*SQ)          // 4096
#define NG 16
#define OUT0 ((size_t)BSQ*EMB)  // 4194304 floats: output region; attn follows

// ---------------------------------------------------------------------------
// Dequant GEMM body: Y[M=4096? rows, 1024] = X[rows,1024] * W^T + bias
//   W[o,e] = (qw[o,e] - zeros[o, e>>6]) * scales[o, e>>6]
// tile: 128 (M) x 64 (N), BK = 16, 256 threads, 8x4 accum per thread
// ---------------------------------------------------------------------------
__device__ __forceinline__ void gemm_dq_body(
        const float* __restrict__ X, const int* __restrict__ qw,
        const float* __restrict__ scales, const float* __restrict__ zeros,
        const float* __restrict__ bias, float* __restrict__ Y,
        int m0, int n0)
{
    __shared__ float Xs[16][132];   // [k][m]  (132: +4 pad keeps 16B align, breaks bank collisions)
    __shared__ float Ws[16][68];    // [k][n]
    const int tid = threadIdx.x;
    const int tx = tid & 15, ty = tid >> 4;
    const int k4 = (tid & 3) * 4;
    const int wrow = tid >> 2;      // 0..63

    float acc[8][4] = {};

    for (int k0 = 0; k0 < EMB; k0 += 16) {
        // stage X tile (128 x 16): 2 float4 per thread
        #pragma unroll
        for (int it = 0; it < 2; ++it) {
            int r = (it*256 + tid) >> 2;   // 0..127
            float4 xv = *(const float4*)&X[(size_t)(m0 + r)*EMB + k0 + k4];
            Xs[k4+0][r] = xv.x; Xs[k4+1][r] = xv.y;
            Xs[k4+2][r] = xv.z; Xs[k4+3][r] = xv.w;
        }
        // stage + dequant W tile (64 x 16): 1 int4 per thread
        {
            int o = n0 + wrow;
            int4 qv = *(const int4*)&qw[(size_t)o*EMB + k0 + k4];
            int g = (k0 + k4) >> 6;
            float zp = zeros[o*NG + g];
            float sc = scales[o*NG + g];
            Ws[k4+0][wrow] = ((float)qv.x - zp) * sc;
            Ws[k4+1][wrow] = ((float)qv.y - zp) * sc;
            Ws[k4+2][wrow] = ((float)qv.z - zp) * sc;
            Ws[k4+3][wrow] = ((float)qv.w - zp) * sc;
        }
        __syncthreads();
        #pragma unroll
        for (int k = 0; k < 16; ++k) {
            float4 a0 = *(const float4*)&Xs[k][ty*8];
            float4 a1 = *(const float4*)&Xs[k][ty*8+4];
            float4 bb = *(const float4*)&Ws[k][tx*4];
            float a[8] = {a0.x,a0.y,a0.z,a0.w,a1.x,a1.y,a1.z,a1.w};
            float bv[4] = {bb.x,bb.y,bb.z,bb.w};
            #pragma unroll
            for (int i = 0; i < 8; ++i)
                #pragma unroll
                for (int j = 0; j < 4; ++j)
                    acc[i][j] += a[i]*bv[j];
        }
        __syncthreads();
    }

    float4 bia = *(const float4*)&bias[n0 + tx*4];
    #pragma unroll
    for (int i = 0; i < 8; ++i) {
        float4 o;
        o.x = acc[i][0] + bia.x;
        o.y = acc[i][1] + bia.y;
        o.z = acc[i][2] + bia.z;
        o.w = acc[i][3] + bia.w;
        *(float4*)&Y[(size_t)(m0 + ty*8 + i)*EMB + n0 + tx*4] = o;
    }
}

// fused Q/K/V projection: blockIdx.z selects the weight set
__global__ __launch_bounds__(256) void qkv_proj(
        const float* __restrict__ X,
        const int* qw0, const float* sc0, const float* zp0, const float* b0, float* y0,
        const int* qw1, const float* sc1, const float* zp1, const float* b1, float* y1,
        const int* qw2, const float* sc2, const float* zp2, const float* b2, float* y2)
{
    const int z = blockIdx.z;
    const int*   qw = (z == 0) ? qw0 : (z == 1) ? qw1 : qw2;
    const float* sc = (z == 0) ? sc0 : (z == 1) ? sc1 : sc2;
    const float* zp = (z == 0) ? zp0 : (z == 1) ? zp1 : zp2;
    const float* bi = (z == 0) ? b0  : (z == 1) ? b1  : b2;
    float*       Y  = (z == 0) ? y0  : (z == 1) ? y1  : y2;
    gemm_dq_body(X, qw, sc, zp, bi, Y, blockIdx.y*128, blockIdx.x*64);
}

__global__ __launch_bounds__(256) void o_proj(
        const float* __restrict__ X, const int* __restrict__ qw,
        const float* __restrict__ sc, const float* __restrict__ zp,
        const float* __restrict__ bi, float* __restrict__ Y)
{
    gemm_dq_body(X, qw, sc, zp, bi, Y, blockIdx.y*128, blockIdx.x*64);
}

// ---------------------------------------------------------------------------
// scores = Q K^T / 8 per (b,h): C[2048,2048] tile 128x64, K=64 (full head dim)
// Q,K stored as [B*S, EMB] with head h at columns h*64..h*64+63
// ---------------------------------------------------------------------------
__global__ __launch_bounds__(256) void qk_score(
        const float* __restrict__ Qm, const float* __restrict__ Km,
        float* __restrict__ Sc)
{
    __shared__ float Qs[64][132];   // [d][row]
    __shared__ float Kt[64][68];    // [d][col]
    const int tid = threadIdx.x;
    const int tx = tid & 15, ty = tid >> 4;
    const int z = blockIdx.z;          // b*16+h
    const int b = z >> 4, h = z & 15;
    const int j0 = blockIdx.x * 64;
    const int i0 = blockIdx.y * 128;
    const float* qbase = Qm + (size_t)(b*SQ)*EMB + h*HD;
    const float* kbase = Km + (size_t)(b*SQ)*EMB + h*HD;

    const int f4 = tid & 15;   // d-quad
    const int rb = tid >> 4;   // 0..15

    #pragma unroll
    for (int it = 0; it < 8; ++it) {
        int r = it*16 + rb;
        float4 v = *(const float4*)&qbase[(size_t)(i0 + r)*EMB + f4*4];
        Qs[f4*4+0][r] = v.x; Qs[f4*4+1][r] = v.y;
        Qs[f4*4+2][r] = v.z; Qs[f4*4+3][r] = v.w;
    }
    #pragma unroll
    for (int it = 0; it < 4; ++it) {
        int c = it*16 + rb;
        float4 v = *(const float4*)&kbase[(size_t)(j0 + c)*EMB + f4*4];
        Kt[f4*4+0][c] = v.x; Kt[f4*4+1][c] = v.y;
        Kt[f4*4+2][c] = v.z; Kt[f4*4+3][c] = v.w;
    }
    __syncthreads();

    float acc[8][4] = {};
    #pragma unroll 16
    for (int k = 0; k < 64; ++k) {
        float4 a0 = *(const float4*)&Qs[k][ty*8];
        float4 a1 = *(const float4*)&Qs[k][ty*8+4];
        float4 bb = *(const float4*)&Kt[k][tx*4];
        float a[8] = {a0.x,a0.y,a0.z,a0.w,a1.x,a1.y,a1.z,a1.w};
        float bv[4] = {bb.x,bb.y,bb.z,bb.w};
        #pragma unroll
        for (int i = 0; i < 8; ++i)
            #pragma unroll
            for (int j = 0; j < 4; ++j)
                acc[i][j] += a[i]*bv[j];
    }

    float* srow = Sc + (size_t)z*SQ*SQ;
    #pragma unroll
    for (int i = 0; i < 8; ++i) {
        float4 o;
        o.x = acc[i][0]*0.125f; o.y = acc[i][1]*0.125f;
        o.z = acc[i][2]*0.125f; o.w = acc[i][3]*0.125f;
        *(float4*)&srow[(size_t)(i0 + ty*8 + i)*SQ + j0 + tx*4] = o;
    }
}

// ---------------------------------------------------------------------------
// in-place row softmax over last dim (2048); one block per row
// ---------------------------------------------------------------------------
__global__ __launch_bounds__(256) void softmax_rows(float* __restrict__ A)
{
    float* p = A + (size_t)blockIdx.x * SQ;
    const int tid = threadIdx.x;
    __shared__ float redm[4];
    __shared__ float reds[4];

    float v[8];
    float m = -INFINITY;
    #pragma unroll
    for (int u = 0; u < 8; ++u) { v[u] = p[tid + u*256]; m = fmaxf(m, v[u]); }
    #pragma unroll
    for (int off = 32; off > 0; off >>= 1) m = fmaxf(m, __shfl_xor(m, off));
    if ((tid & 63) == 0) redm[tid >> 6] = m;
    __syncthreads();
    m = fmaxf(fmaxf(redm[0], redm[1]), fmaxf(redm[2], redm[3]));

    float s = 0.f;
    #pragma unroll
    for (int u = 0; u < 8; ++u) { v[u] = __expf(v[u] - m); s += v[u]; }
    #pragma unroll
    for (int off = 32; off > 0; off >>= 1) s += __shfl_xor(s, off);
    if ((tid & 63) == 0) reds[tid >> 6] = s;
    __syncthreads();
    s = reds[0] + reds[1] + reds[2] + reds[3];

    float inv = 1.0f / s;
    #pragma unroll
    for (int u = 0; u < 8; ++u) p[tid + u*256] = v[u] * inv;
}

// ---------------------------------------------------------------------------
// attn_out = P V per (b,h): C[2048,64], tile 128 rows x 64 (full D), BK=64
// ---------------------------------------------------------------------------
__global__ __launch_bounds__(256) void pv_kernel(
        const float* __restrict__ P, const float* __restrict__ Vm,
        float* __restrict__ AO)
{
    __shared__ float Pt[64][132];  // [j][row]
    __shared__ float Vs[64][68];   // [j][d]
    const int tid = threadIdx.x;
    const int tx = tid & 15, ty = tid >> 4;
    const int z = blockIdx.y;      // b*16+h
    const int b = z >> 4, h = z & 15;
    const int i0 = blockIdx.x * 128;
    const float* pbase = P + (size_t)z*SQ*SQ;
    const float* vbase = Vm + (size_t)(b*SQ)*EMB + h*HD;
    const int f4 = tid & 15, rb = tid >> 4;

    float acc[8][4] = {};
    for (int j0 = 0; j0 < SQ; j0 += 64) {
        #pragma unroll
        for (int it = 0; it < 8; ++it) {
            int r = it*16 + rb;
            float4 v = *(const float4*)&pbase[(size_t)(i0 + r)*SQ + j0 + f4*4];
            Pt[f4*4+0][r] = v.x; Pt[f4*4+1][r] = v.y;
            Pt[f4*4+2][r] = v.z; Pt[f4*4+3][r] = v.w;
        }
        #pragma unroll
        for (int it = 0; it < 4; ++it) {
            int j = it*16 + rb;
            float4 v = *(const float4*)&vbase[(size_t)(j0 + j)*EMB + f4*4];
            *(float4*)&Vs[j][f4*4] = v;
        }
        __syncthreads();
        #pragma unroll 16
        for (int k = 0; k < 64; ++k) {
            float4 a0 = *(const float4*)&Pt[k][ty*8];
            float4 a1 = *(const float4*)&Pt[k][ty*8+4];
            float4 bb = *(const float4*)&Vs[k][tx*4];
            float a[8] = {a0.x,a0.y,a0.z,a0.w,a1.x,a1.y,a1.z,a1.w};
            float bv[4] = {bb.x,bb.y,bb.z,bb.w};
            #pragma unroll
            for (int i = 0; i < 8; ++i)
                #pragma unroll
                for (int j = 0; j < 4; ++j)
                    acc[i][j] += a[i]*bv[j];
        }
        __syncthreads();
    }

    #pragma unroll
    for (int i = 0; i < 8; ++i) {
        float4 o;
        o.x = acc[i][0]; o.y = acc[i][1]; o.z = acc[i][2]; o.w = acc[i][3];
        *(float4*)&AO[(size_t)(b*SQ + i0 + ty*8 + i)*EMB + h*HD + tx*4] = o;
    }
}

// ---------------------------------------------------------------------------
extern "C" void kernel_launch(void* const* d_in, const int* in_sizes, int n_in,
                              void* d_out, int out_size, void* d_ws, size_t ws_size,
                              hipStream_t stream)
{
    const float* hs   = (const float*)d_in[0];
    const int*   q_qw = (const int*)  d_in[1];
    const float* q_sc = (const float*)d_in[2];
    const float* q_zp = (const float*)d_in[3];
    const float* q_b  = (const float*)d_in[4];
    const int*   k_qw = (const int*)  d_in[5];
    const float* k_sc = (const float*)d_in[6];
    const float* k_zp = (const float*)d_in[7];
    const float* k_b  = (const float*)d_in[8];
    const int*   v_qw = (const int*)  d_in[9];
    const float* v_sc = (const float*)d_in[10];
    const float* v_zp = (const float*)d_in[11];
    const float* v_b  = (const float*)d_in[12];
    const int*   o_qw = (const int*)  d_in[13];
    const float* o_sc = (const float*)d_in[14];
    const float* o_zp = (const float*)d_in[15];
    const float* o_b  = (const float*)d_in[16];

    float* out  = (float*)d_out;
    float* attn = out + OUT0;                  // [B,H,S,S] region (final attn_weights)

    float* qbuf  = (float*)d_ws;
    float* kbuf  = qbuf + (size_t)BSQ*EMB;
    float* vbuf  = kbuf + (size_t)BSQ*EMB;
    float* aobuf = vbuf + (size_t)BSQ*EMB;

    dim3 blk(256);

    // 1. Q,K,V projections (fused over grid.z)
    qkv_proj<<<dim3(EMB/64, BSQ/128, 3), blk, 0, stream>>>(
        hs,
        q_qw, q_sc, q_zp, q_b, qbuf,
        k_qw, k_sc, k_zp, k_b, kbuf,
        v_qw, v_sc, v_zp, v_b, vbuf);

    // 2. raw scores into attn region of d_out
    qk_score<<<dim3(SQ/64, SQ/128, NB*NH), blk, 0, stream>>>(qbuf, kbuf, attn);

    // 3. softmax in place (these are the final attn_weights)
    softmax_rows<<<dim3(NB*NH*SQ), blk, 0, stream>>>(attn);

    // 4. attn_out = P V
    pv_kernel<<<dim3(SQ/128, NB*NH), blk, 0, stream>>>(attn, vbuf, aobuf);

    // 5. output projection
    o_proj<<<dim3(EMB/64, BSQ/128), blk, 0, stream>>>(
        aobuf, o_qw, o_sc, o_zp, o_b, out);
}

// Round 2
// 1124.328 us; speedup vs baseline: 1.4641x; 1.4641x over previous
//
#include <hip/hip_runtime.h>
#include <math.h>

#define EMB 1024
#define NH 16
#define HD 64
#define NB 2
#define SQ 2048
#define BSQ (NB*SQ)          // 4096
#define NG 16
#define OUT0 ((size_t)BSQ*EMB)  // output region floats; attn follows in d_out

typedef __attribute__((ext_vector_type(8))) short bf16x8;
typedef __attribute__((ext_vector_type(4))) float f32x4;

__device__ __forceinline__ short f2bf(float x){
    unsigned u = __float_as_uint(x);
    u += 0x7fff + ((u >> 16) & 1);     // RNE
    return (short)(u >> 16);
}
__device__ __forceinline__ float bf2f(short h){
    return __uint_as_float(((unsigned)(unsigned short)h) << 16);
}

// ---------------------------------------------------------------------------
// Generic MFMA GEMM: C[M,N] = scale * A[M,K] * B[N,K]^T + bias
// A, B are fp32 in global; staged into LDS as bf16 hi(/lo) during load.
// TERMS==3: hh + hl + lh split-precision (near-fp32).  TERMS==1: plain bf16.
// BM=128 fixed. 256 threads = 4 waves, wave grid WR x WC.
// TRANSB: B source is [K,N] row-major (ldb = row stride), transposed in LDS.
// ---------------------------------------------------------------------------
template<int TERMS, int BN, int WR, int WC, bool TRANSB>
__device__ __forceinline__ void gemm_body(
        const float* __restrict__ A, int lda,
        const float* __restrict__ B, int ldb, int K,
        float* __restrict__ C, long long ldc,
        const float* __restrict__ bias, float scale,
        int m0, int n0)
{
    constexpr int BM = 128;
    constexpr int LSTR = 40;              // padded k-stride (shorts): 2-way banks only
    constexpr int ASZ = BM*LSTR;
    constexpr int BSZ = BN*LSTR;
    constexpr bool SPL = (TERMS > 1);
    static_assert(TRANSB || BN == 128, "non-trans staging assumes BN==128");
    static_assert(!TRANSB || (BN == 64 && TERMS == 1), "trans staging is BN=64, 1-term");

    __shared__ short lds[ASZ*(SPL?2:1) + BSZ*(SPL?2:1)];
    short* Ah = lds;
    short* Al = lds + (SPL ? ASZ : 0);
    short* Bh = lds + ASZ*(SPL?2:1);
    short* Bl = Bh + (SPL ? BSZ : 0);

    const int tid = threadIdx.x;
    const int w = tid >> 6;
    const int l = tid & 63;
    const int lrow = l & 15;
    const int lq = l >> 4;
    constexpr int WTM = BM / WR;
    constexpr int WTN = BN / WC;
    constexpr int MI = WTM / 16;
    constexpr int NJ = WTN / 16;
    const int wr = w / WC;
    const int wc = w % WC;

    f32x4 zero4 = {0.f, 0.f, 0.f, 0.f};
    f32x4 acc[MI][NJ];
    #pragma unroll
    for (int i = 0; i < MI; ++i)
        #pragma unroll
        for (int j = 0; j < NJ; ++j) acc[i][j] = zero4;

    for (int k0 = 0; k0 < K; k0 += 32) {
        // ---- stage A tile: 128 rows x 32 k, each thread 16 elems ----
        {
            int r = tid >> 1;
            int kh = (tid & 1) * 16;
            const float* src = A + (size_t)(m0 + r)*lda + k0 + kh;
            float4 v0 = *(const float4*)(src);
            float4 v1 = *(const float4*)(src + 4);
            float4 v2 = *(const float4*)(src + 8);
            float4 v3 = *(const float4*)(src + 12);
            float xv[16] = {v0.x,v0.y,v0.z,v0.w, v1.x,v1.y,v1.z,v1.w,
                            v2.x,v2.y,v2.z,v2.w, v3.x,v3.y,v3.z,v3.w};
            alignas(16) short hv[16];
            alignas(16) short lv[16];
            #pragma unroll
            for (int j = 0; j < 16; ++j) {
                short h = f2bf(xv[j]); hv[j] = h;
                if (SPL) lv[j] = f2bf(xv[j] - bf2f(h));
            }
            *(bf16x8*)(Ah + r*LSTR + kh)     = ((const bf16x8*)hv)[0];
            *(bf16x8*)(Ah + r*LSTR + kh + 8) = ((const bf16x8*)hv)[1];
            if (SPL) {
                *(bf16x8*)(Al + r*LSTR + kh)     = ((const bf16x8*)lv)[0];
                *(bf16x8*)(Al + r*LSTR + kh + 8) = ((const bf16x8*)lv)[1];
            }
        }
        // ---- stage B tile ----
        if (!TRANSB) {
            int r = tid >> 1;
            int kh = (tid & 1) * 16;
            const float* src = B + (size_t)(n0 + r)*ldb + k0 + kh;
            float4 v0 = *(const float4*)(src);
            float4 v1 = *(const float4*)(src + 4);
            float4 v2 = *(const float4*)(src + 8);
            float4 v3 = *(const float4*)(src + 12);
            float xv[16] = {v0.x,v0.y,v0.z,v0.w, v1.x,v1.y,v1.z,v1.w,
                            v2.x,v2.y,v2.z,v2.w, v3.x,v3.y,v3.z,v3.w};
            alignas(16) short hv[16];
            alignas(16) short lv[16];
            #pragma unroll
            for (int j = 0; j < 16; ++j) {
                short h = f2bf(xv[j]); hv[j] = h;
                if (SPL) lv[j] = f2bf(xv[j] - bf2f(h));
            }
            *(bf16x8*)(Bh + r*LSTR + kh)     = ((const bf16x8*)hv)[0];
            *(bf16x8*)(Bh + r*LSTR + kh + 8) = ((const bf16x8*)hv)[1];
            if (SPL) {
                *(bf16x8*)(Bl + r*LSTR + kh)     = ((const bf16x8*)lv)[0];
                *(bf16x8*)(Bl + r*LSTR + kh + 8) = ((const bf16x8*)lv)[1];
            }
        } else {
            // B source [K,N]: rows t = k0..k0+31, cols n0..n0+63; write LDS transposed
            int tt = tid >> 3;            // 0..31 (k within tile)
            int d0 = (tid & 7) * 8;       // 0..56 (n)
            const float* src = B + (size_t)(k0 + tt)*ldb + n0 + d0;
            float4 v0 = *(const float4*)(src);
            float4 v1 = *(const float4*)(src + 4);
            float dv[8] = {v0.x,v0.y,v0.z,v0.w, v1.x,v1.y,v1.z,v1.w};
            #pragma unroll
            for (int j = 0; j < 8; ++j)
                Bh[(d0 + j)*LSTR + tt] = f2bf(dv[j]);
        }
        __syncthreads();

        // ---- fragments + MFMA ----
        bf16x8 aH[MI], aL[MI], bH[NJ], bL[NJ];
        #pragma unroll
        for (int i = 0; i < MI; ++i) {
            int row = wr*WTM + i*16 + lrow;
            aH[i] = *(const bf16x8*)(Ah + row*LSTR + lq*8);
            if (SPL) aL[i] = *(const bf16x8*)(Al + row*LSTR + lq*8);
        }
        #pragma unroll
        for (int j = 0; j < NJ; ++j) {
            int col = wc*WTN + j*16 + lrow;
            bH[j] = *(const bf16x8*)(Bh + col*LSTR + lq*8);
            if (SPL) bL[j] = *(const bf16x8*)(Bl + col*LSTR + lq*8);
        }
        #pragma unroll
        for (int i = 0; i < MI; ++i)
            #pragma unroll
            for (int j = 0; j < NJ; ++j) {
                acc[i][j] = __builtin_amdgcn_mfma_f32_16x16x32_bf16(aH[i], bH[j], acc[i][j], 0, 0, 0);
                if (SPL) {
                    acc[i][j] = __builtin_amdgcn_mfma_f32_16x16x32_bf16(aH[i], bL[j], acc[i][j], 0, 0, 0);
                    acc[i][j] = __builtin_amdgcn_mfma_f32_16x16x32_bf16(aL[i], bH[j], acc[i][j], 0, 0, 0);
                }
            }
        __syncthreads();
    }

    // ---- epilogue: C/D layout col=lane&15, row=(lane>>4)*4+reg ----
    #pragma unroll
    for (int i = 0; i < MI; ++i) {
        int rb = m0 + wr*WTM + i*16 + lq*4;
        #pragma unroll
        for (int j = 0; j < NJ; ++j) {
            int cb = n0 + wc*WTN + j*16 + lrow;
            float bv = bias ? bias[cb] : 0.f;
            #pragma unroll
            for (int r = 0; r < 4; ++r)
                C[(size_t)(rb + r)*ldc + cb] = acc[i][j][r]*scale + bv;
        }
    }
}

// ---------------------------------------------------------------------------
// dequant weights -> fp32 (4 projections via grid.z)
// ---------------------------------------------------------------------------
__global__ __launch_bounds__(256) void prep_w(
        const int* qq, const float* qs, const float* qz,
        const int* kq, const float* ks, const float* kz,
        const int* vq, const float* vs, const float* vz,
        const int* oq, const float* os, const float* oz,
        float* Wf)
{
    int z = blockIdx.z;
    const int*   qw = z==0?qq : z==1?kq : z==2?vq : oq;
    const float* sc = z==0?qs : z==1?ks : z==2?vs : os;
    const float* zp = z==0?qz : z==1?kz : z==2?vz : oz;
    float* W = Wf + (size_t)z*EMB*EMB;
    int idx = (blockIdx.x*256 + threadIdx.x)*4;
    int4 q4 = *(const int4*)(qw + idx);
    int o = idx >> 10, g = (idx & 1023) >> 6;
    float s = sc[o*NG + g], zv = zp[o*NG + g];
    float4 wv;
    wv.x = ((float)q4.x - zv)*s; wv.y = ((float)q4.y - zv)*s;
    wv.z = ((float)q4.z - zv)*s; wv.w = ((float)q4.w - zv)*s;
    *(float4*)(W + idx) = wv;
}

__global__ __launch_bounds__(256) void k_qkv(
        const float* __restrict__ X, const float* __restrict__ Wf,
        const float* bq, const float* bk, const float* bv,
        float* Q, float* Kf, float* V)
{
    int z = blockIdx.z;
    const float* W    = Wf + (size_t)z*EMB*EMB;
    const float* bias = z==0?bq : z==1?bk : bv;
    float*       Y    = z==0?Q  : z==1?Kf : V;
    gemm_body<3,128,2,2,false>(X, EMB, W, EMB, EMB, Y, EMB, bias, 1.f,
                               blockIdx.y*128, blockIdx.x*128);
}

__global__ __launch_bounds__(256) void k_qk(
        const float* __restrict__ Q, const float* __restrict__ Kf,
        float* __restrict__ attn)
{
    int z = blockIdx.z; int b = z >> 4, h = z & 15;
    const float* Ab = Q  + (size_t)b*SQ*EMB + h*HD;
    const float* Bb = Kf + (size_t)b*SQ*EMB + h*HD;
    float* Cb = attn + (size_t)z*SQ*SQ;
    gemm_body<3,128,2,2,false>(Ab, EMB, Bb, EMB, HD, Cb, SQ, nullptr, 0.125f,
                               blockIdx.y*128, blockIdx.x*128);
}

__global__ __launch_bounds__(256) void k_pv(
        const float* __restrict__ attn, const float* __restrict__ V,
        float* __restrict__ AO)
{
    int z = blockIdx.z; int b = z >> 4, h = z & 15;
    const float* Ab = attn + (size_t)z*SQ*SQ;
    const float* Bb = V  + (size_t)b*SQ*EMB + h*HD;   // [t, d] rows, TRANSB
    float* Cb = AO + (size_t)b*SQ*EMB + h*HD;
    gemm_body<1,64,4,1,true>(Ab, SQ, Bb, EMB, SQ, Cb, EMB, nullptr, 1.f,
                             blockIdx.y*128, 0);
}

__global__ __launch_bounds__(256) void k_o(
        const float* __restrict__ AO, const float* __restrict__ Wo,
        const float* bo, float* __restrict__ out)
{
    gemm_body<1,128,2,2,false>(AO, EMB, Wo, EMB, EMB, out, EMB, bo, 1.f,
                               blockIdx.y*128, blockIdx.x*128);
}

// ---------------------------------------------------------------------------
// in-place row softmax over last dim (2048); one block per row
// ---------------------------------------------------------------------------
__global__ __launch_bounds__(256) void softmax_rows(float* __restrict__ A)
{
    float* p = A + (size_t)blockIdx.x * SQ;
    const int tid = threadIdx.x;
    __shared__ float redm[4];
    __shared__ float reds[4];

    float v[8];
    float m = -INFINITY;
    #pragma unroll
    for (int u = 0; u < 8; ++u) { v[u] = p[tid + u*256]; m = fmaxf(m, v[u]); }
    #pragma unroll
    for (int off = 32; off > 0; off >>= 1) m = fmaxf(m, __shfl_xor(m, off));
    if ((tid & 63) == 0) redm[tid >> 6] = m;
    __syncthreads();
    m = fmaxf(fmaxf(redm[0], redm[1]), fmaxf(redm[2], redm[3]));

    float s = 0.f;
    #pragma unroll
    for (int u = 0; u < 8; ++u) { v[u] = __expf(v[u] - m); s += v[u]; }
    #pragma unroll
    for (int off = 32; off > 0; off >>= 1) s += __shfl_xor(s, off);
    if ((tid & 63) == 0) reds[tid >> 6] = s;
    __syncthreads();
    s = reds[0] + reds[1] + reds[2] + reds[3];

    float inv = 1.0f / s;
    #pragma unroll
    for (int u = 0; u < 8; ++u) p[tid + u*256] = v[u] * inv;
}

// ---------------------------------------------------------------------------
extern "C" void kernel_launch(void* const* d_in, const int* in_sizes, int n_in,
                              void* d_out, int out_size, void* d_ws, size_t ws_size,
                              hipStream_t stream)
{
    const float* hs   = (const float*)d_in[0];
    const int*   q_qw = (const int*)  d_in[1];
    const float* q_sc = (const float*)d_in[2];
    const float* q_zp = (const float*)d_in[3];
    const float* q_b  = (const float*)d_in[4];
    const int*   k_qw = (const int*)  d_in[5];
    const float* k_sc = (const float*)d_in[6];
    const float* k_zp = (const float*)d_in[7];
    const float* k_b  = (const float*)d_in[8];
    const int*   v_qw = (const int*)  d_in[9];
    const float* v_sc = (const float*)d_in[10];
    const float* v_zp = (const float*)d_in[11];
    const float* v_b  = (const float*)d_in[12];
    const int*   o_qw = (const int*)  d_in[13];
    const float* o_sc = (const float*)d_in[14];
    const float* o_zp = (const float*)d_in[15];
    const float* o_b  = (const float*)d_in[16];

    float* out  = (float*)d_out;
    float* attn = out + OUT0;

    // ws layout (floats): Wf[4M] | Qf[4M] | Kf[4M] | Vf[4M]; AOf overlays Qf
    float* Wf  = (float*)d_ws;
    float* Qf  = Wf + (size_t)4*EMB*EMB;
    float* Kf  = Qf + (size_t)BSQ*EMB;
    float* Vf  = Kf + (size_t)BSQ*EMB;
    float* AOf = Qf;   // Q dead after k_qk

    dim3 blk(256);

    prep_w<<<dim3(EMB*EMB/1024, 1, 4), blk, 0, stream>>>(
        q_qw, q_sc, q_zp, k_qw, k_sc, k_zp,
        v_qw, v_sc, v_zp, o_qw, o_sc, o_zp, Wf);

    k_qkv<<<dim3(EMB/128, BSQ/128, 3), blk, 0, stream>>>(
        hs, Wf, q_b, k_b, v_b, Qf, Kf, Vf);

    k_qk<<<dim3(SQ/128, SQ/128, NB*NH), blk, 0, stream>>>(Qf, Kf, attn);

    softmax_rows<<<dim3(NB*NH*SQ), blk, 0, stream>>>(attn);

    k_pv<<<dim3(1, SQ/128, NB*NH), blk, 0, stream>>>(attn, Vf, AOf);

    k_o<<<dim3(EMB/128, BSQ/128, 1), blk, 0, stream>>>(AOf, Wf + (size_t)3*EMB*EMB, o_b, out);
}

// Round 5
// 898.123 us; speedup vs baseline: 1.8328x; 1.2519x over previous
//
#include <hip/hip_runtime.h>
#include <math.h>

#define EMB 1024
#define NH 16
#define HD 64
#define NB 2
#define SQ 2048
#define BSQ (NB*SQ)
#define NG 16
#define OUT0 ((size_t)BSQ*EMB)

typedef __attribute__((ext_vector_type(8))) short bf16x8;
typedef __attribute__((ext_vector_type(4))) float f32x4;

__device__ __forceinline__ short f2bf(float x){
    unsigned u = __float_as_uint(x);
    u += 0x7fff + ((u >> 16) & 1);     // RNE
    return (short)(u >> 16);
}
__device__ __forceinline__ float bf2f(short h){
    return __uint_as_float(((unsigned)(unsigned short)h) << 16);
}

// ---------------------------------------------------------------------------
// dequant weights -> bf16 hi (all 4) + lo (q,k only)
// ---------------------------------------------------------------------------
__global__ __launch_bounds__(256) void prep_w(
        const int* qq, const float* qs, const float* qz,
        const int* kq, const float* ks, const float* kz,
        const int* vq, const float* vs, const float* vz,
        const int* oq, const float* os, const float* oz,
        short* __restrict__ Wh, short* __restrict__ Wl)
{
    int z = blockIdx.z;
    const int*   qw = z==0?qq : z==1?kq : z==2?vq : oq;
    const float* sc = z==0?qs : z==1?ks : z==2?vs : os;
    const float* zp = z==0?qz : z==1?kz : z==2?vz : oz;
    size_t base = (size_t)z*EMB*EMB;
    int idx = (blockIdx.x*256 + threadIdx.x)*8;
    int4 a = *(const int4*)(qw + idx);
    int4 b = *(const int4*)(qw + idx + 4);
    int o = idx >> 10, g = (idx & 1023) >> 6;
    float s = sc[o*NG + g], zv = zp[o*NG + g];
    int qv[8] = {a.x,a.y,a.z,a.w,b.x,b.y,b.z,b.w};
    alignas(16) short hv[8];
    alignas(16) short lv[8];
    #pragma unroll
    for (int j = 0; j < 8; ++j) {
        float wv = ((float)qv[j] - zv)*s;
        short h = f2bf(wv); hv[j] = h;
        lv[j] = f2bf(wv - bf2f(h));
    }
    *(bf16x8*)(Wh + base + idx) = *(const bf16x8*)hv;
    if (z < 2)
        *(bf16x8*)(Wl + base + idx) = *(const bf16x8*)lv;
}

__global__ __launch_bounds__(256) void prep_x(
        const float* __restrict__ X, short* __restrict__ Xh, short* __restrict__ Xl)
{
    int idx = (blockIdx.x*256 + threadIdx.x)*8;
    float4 a = *(const float4*)(X + idx);
    float4 b = *(const float4*)(X + idx + 4);
    float xv[8] = {a.x,a.y,a.z,a.w,b.x,b.y,b.z,b.w};
    alignas(16) short hv[8];
    alignas(16) short lv[8];
    #pragma unroll
    for (int j = 0; j < 8; ++j) {
        short h = f2bf(xv[j]); hv[j] = h;
        lv[j] = f2bf(xv[j] - bf2f(h));
    }
    *(bf16x8*)(Xh + idx) = *(const bf16x8*)hv;
    *(bf16x8*)(Xl + idx) = *(const bf16x8*)lv;
}

// ---------------------------------------------------------------------------
// bf16 MFMA GEMM: C[4096,1024] = A[4096,1024] * B[1024,1024]^T + bias
// TERMS=3: hh+hl+lh split.  TERMS=1: plain bf16.
// EPI: 0 = bf16 hi/lo pair; 2 = fp32; 3 = V-mode transposed bf16 -> Vt[z][d][s]
// 128x128 tile, BK=32, 4 waves (2x2).
// ---------------------------------------------------------------------------
template<int TERMS, int EPI>
__global__ __launch_bounds__(256, 2) void k_proj(
        const short* __restrict__ Ahg, const short* __restrict__ Alg,
        const short* __restrict__ Bhg, const short* __restrict__ Blg,
        const float* __restrict__ bias,
        short* __restrict__ outH, short* __restrict__ outL,
        float* __restrict__ outF)
{
    constexpr bool SPL = (TERMS > 1);
    constexpr int LSTR = 40;
    constexpr int MSZ  = 128*LSTR*(SPL?2:1);      // per-matrix stage (shorts)
    constexpr int STAGE = 2*MSZ;
    constexpr int TSH  = (EPI == 3) ? 128*136 : 0;
    constexpr int LDSN = (STAGE > TSH) ? STAGE : TSH;
    __shared__ short lds[LDSN];
    short* As  = lds;
    short* Bs  = lds + MSZ;
    short* Asl = As + 128*LSTR;
    short* Bsl = Bs + 128*LSTR;

    const int tid = threadIdx.x;
    const int l = tid & 63, w = tid >> 6;
    const int lrow = l & 15, lq = l >> 4;
    const int wr = w >> 1, wc = w & 1;
    const int m0 = blockIdx.y*128, n0 = blockIdx.x*128;
    const int r = tid >> 1, kh = (tid & 1)*16;

    f32x4 acc[4][4] = {};

    for (int k0 = 0; k0 < EMB; k0 += 32) {
        const short* as = Ahg + (size_t)(m0 + r)*EMB + k0 + kh;
        bf16x8 a0 = *(const bf16x8*)as;
        bf16x8 a1 = *(const bf16x8*)(as + 8);
        const short* bs = Bhg + (size_t)(n0 + r)*EMB + k0 + kh;
        bf16x8 b0 = *(const bf16x8*)bs;
        bf16x8 b1 = *(const bf16x8*)(bs + 8);
        bf16x8 a2{}, a3{}, b2{}, b3{};
        if constexpr (SPL) {
            const short* as2 = Alg + (size_t)(m0 + r)*EMB + k0 + kh;
            a2 = *(const bf16x8*)as2; a3 = *(const bf16x8*)(as2 + 8);
            const short* bs2 = Blg + (size_t)(n0 + r)*EMB + k0 + kh;
            b2 = *(const bf16x8*)bs2; b3 = *(const bf16x8*)(bs2 + 8);
        }
        __syncthreads();
        *(bf16x8*)(As + r*LSTR + kh)     = a0;
        *(bf16x8*)(As + r*LSTR + kh + 8) = a1;
        *(bf16x8*)(Bs + r*LSTR + kh)     = b0;
        *(bf16x8*)(Bs + r*LSTR + kh + 8) = b1;
        if constexpr (SPL) {
            *(bf16x8*)(Asl + r*LSTR + kh)     = a2;
            *(bf16x8*)(Asl + r*LSTR + kh + 8) = a3;
            *(bf16x8*)(Bsl + r*LSTR + kh)     = b2;
            *(bf16x8*)(Bsl + r*LSTR + kh + 8) = b3;
        }
        __syncthreads();

        bf16x8 aH[4], aL[4], bH[4], bL[4];
        #pragma unroll
        for (int i = 0; i < 4; ++i) {
            aH[i] = *(const bf16x8*)(As + (wr*64 + i*16 + lrow)*LSTR + lq*8);
            if constexpr (SPL) aL[i] = *(const bf16x8*)(Asl + (wr*64 + i*16 + lrow)*LSTR + lq*8);
        }
        #pragma unroll
        for (int j = 0; j < 4; ++j) {
            bH[j] = *(const bf16x8*)(Bs + (wc*64 + j*16 + lrow)*LSTR + lq*8);
            if constexpr (SPL) bL[j] = *(const bf16x8*)(Bsl + (wc*64 + j*16 + lrow)*LSTR + lq*8);
        }
        #pragma unroll
        for (int i = 0; i < 4; ++i)
            #pragma unroll
            for (int j = 0; j < 4; ++j) {
                acc[i][j] = __builtin_amdgcn_mfma_f32_16x16x32_bf16(aH[i], bH[j], acc[i][j], 0, 0, 0);
                if constexpr (SPL) {
                    acc[i][j] = __builtin_amdgcn_mfma_f32_16x16x32_bf16(aH[i], bL[j], acc[i][j], 0, 0, 0);
                    acc[i][j] = __builtin_amdgcn_mfma_f32_16x16x32_bf16(aL[i], bH[j], acc[i][j], 0, 0, 0);
                }
            }
    }

    if constexpr (EPI == 3) {
        // transpose through LDS, write Vt[z][d][s] coalesced along s
        __syncthreads();
        #pragma unroll
        for (int i = 0; i < 4; ++i) {
            int rl = wr*64 + i*16 + lq*4;
            #pragma unroll
            for (int j = 0; j < 4; ++j) {
                int cl = wc*64 + j*16 + lrow;
                float bv = bias[n0 + cl];
                #pragma unroll
                for (int rr = 0; rr < 4; ++rr)
                    lds[cl*136 + rl + rr] = f2bf(acc[i][j][rr] + bv);
            }
        }
        __syncthreads();
        int c = tid >> 1, hf = (tid & 1)*64;
        int gc = n0 + c;
        int z2 = (m0 >> 11)*16 + (gc >> 6);
        int d = gc & 63;
        short* dst = outH + ((size_t)z2*HD + d)*SQ + (m0 & (SQ-1)) + hf;
        #pragma unroll
        for (int u = 0; u < 8; ++u)
            *(bf16x8*)(dst + u*8) = *(const bf16x8*)(lds + c*136 + hf + u*8);
        return;
    }

    #pragma unroll
    for (int i = 0; i < 4; ++i) {
        int rb = m0 + wr*64 + i*16 + lq*4;
        #pragma unroll
        for (int j = 0; j < 4; ++j) {
            int cb = n0 + wc*64 + j*16 + lrow;
            float bv = bias[cb];
            #pragma unroll
            for (int rr = 0; rr < 4; ++rr) {
                float y = acc[i][j][rr] + bv;
                size_t off = (size_t)(rb + rr)*EMB + cb;
                if constexpr (EPI == 0) {
                    short hh = f2bf(y);
                    outH[off] = hh;
                    outL[off] = f2bf(y - bf2f(hh));
                } else {
                    outF[off] = y;
                }
            }
        }
    }
}

// ---------------------------------------------------------------------------
// attention, two passes over an identical score computation.
// PASS1: row max + denominator -> ml.  PASS2: normalized P write + P*V.
// ---------------------------------------------------------------------------
template<int PASS>
__global__ __launch_bounds__(256, 2) void k_attn(
        const short* __restrict__ Qh, const short* __restrict__ Ql,
        const short* __restrict__ Kh, const short* __restrict__ Kl,
        const short* __restrict__ Vt,
        float* __restrict__ ml,
        float* __restrict__ attn,
        short* __restrict__ AO)
{
    constexpr int LSTR = 72;                 // 64 + 8 pad
    __shared__ short qbuf[128*LSTR*2];       // hi | lo ; reused as P tile in PASS2
    __shared__ short kbuf[64*LSTR*2];        // hi | lo
    __shared__ short vbuf[(PASS==2) ? 64*LSTR : 8];
    constexpr int QOFF = 128*LSTR;
    constexpr int KOFF = 64*LSTR;

    const int tid = threadIdx.x;
    const int l = tid & 63, w = tid >> 6;
    const int lrow = l & 15, lq = l >> 4;
    const int z = blockIdx.y, b = z >> 4, h = z & 15;
    const int i0 = blockIdx.x*128;
    const size_t qrow0 = (size_t)(b*SQ + i0);
    const size_t zbase = (size_t)z*SQ*SQ;

    {
        int rr = tid >> 1, kh2 = (tid & 1)*32;
        const short* qh = Qh + (qrow0 + rr)*EMB + h*HD + kh2;
        const short* ql = Ql + (qrow0 + rr)*EMB + h*HD + kh2;
        #pragma unroll
        for (int u = 0; u < 4; ++u) {
            *(bf16x8*)(qbuf + rr*LSTR + kh2 + u*8)        = *(const bf16x8*)(qh + u*8);
            *(bf16x8*)(qbuf + QOFF + rr*LSTR + kh2 + u*8) = *(const bf16x8*)(ql + u*8);
        }
    }
    __syncthreads();
    bf16x8 aH[2][2], aL[2][2];
    #pragma unroll
    for (int i = 0; i < 2; ++i)
        #pragma unroll
        for (int ks = 0; ks < 2; ++ks) {
            aH[i][ks] = *(const bf16x8*)(qbuf + (w*32 + i*16 + lrow)*LSTR + ks*32 + lq*8);
            aL[i][ks] = *(const bf16x8*)(qbuf + QOFF + (w*32 + i*16 + lrow)*LSTR + ks*32 + lq*8);
        }

    float m_st[2][4], l_st[2][4];
    #pragma unroll
    for (int i = 0; i < 2; ++i)
        #pragma unroll
        for (int rr = 0; rr < 4; ++rr) {
            if constexpr (PASS == 1) {
                m_st[i][rr] = -INFINITY; l_st[i][rr] = 0.f;
            } else {
                int row = i0 + w*32 + i*16 + lq*4 + rr;
                m_st[i][rr] = ml[(size_t)z*SQ + row];
                l_st[i][rr] = 1.0f / ml[(size_t)NB*NH*SQ + (size_t)z*SQ + row];
            }
        }

    f32x4 oa[2][4] = {};

    for (int j0 = 0; j0 < SQ; j0 += 64) {
        // stage K (hi/lo) and V: 64 rows x 64 shorts; 4 threads/row x 16 shorts
        int c = tid >> 2, kh2 = (tid & 3)*16;
        const short* khp = Kh + (size_t)(b*SQ + j0 + c)*EMB + h*HD + kh2;
        const short* klp = Kl + (size_t)(b*SQ + j0 + c)*EMB + h*HD + kh2;
        bf16x8 k0a = *(const bf16x8*)khp;
        bf16x8 k0b = *(const bf16x8*)(khp + 8);
        bf16x8 k1a = *(const bf16x8*)klp;
        bf16x8 k1b = *(const bf16x8*)(klp + 8);
        bf16x8 va{}, vb{};
        if constexpr (PASS == 2) {
            const short* vp = Vt + ((size_t)z*HD + c)*SQ + j0 + kh2;
            va = *(const bf16x8*)vp;
            vb = *(const bf16x8*)(vp + 8);
        }
        __syncthreads();
        *(bf16x8*)(kbuf + c*LSTR + kh2)            = k0a;
        *(bf16x8*)(kbuf + c*LSTR + kh2 + 8)        = k0b;
        *(bf16x8*)(kbuf + KOFF + c*LSTR + kh2)     = k1a;
        *(bf16x8*)(kbuf + KOFF + c*LSTR + kh2 + 8) = k1b;
        if constexpr (PASS == 2) {
            *(bf16x8*)(vbuf + c*LSTR + kh2)     = va;
            *(bf16x8*)(vbuf + c*LSTR + kh2 + 8) = vb;
        }
        __syncthreads();

        f32x4 acc[2][4] = {};
        #pragma unroll
        for (int ks = 0; ks < 2; ++ks) {
            bf16x8 bH[4], bL[4];
            #pragma unroll
            for (int jj = 0; jj < 4; ++jj) {
                bH[jj] = *(const bf16x8*)(kbuf + (jj*16 + lrow)*LSTR + ks*32 + lq*8);
                bL[jj] = *(const bf16x8*)(kbuf + KOFF + (jj*16 + lrow)*LSTR + ks*32 + lq*8);
            }
            #pragma unroll
            for (int i = 0; i < 2; ++i)
                #pragma unroll
                for (int jj = 0; jj < 4; ++jj) {
                    acc[i][jj] = __builtin_amdgcn_mfma_f32_16x16x32_bf16(aH[i][ks], bH[jj], acc[i][jj], 0, 0, 0);
                    acc[i][jj] = __builtin_amdgcn_mfma_f32_16x16x32_bf16(aH[i][ks], bL[jj], acc[i][jj], 0, 0, 0);
                    acc[i][jj] = __builtin_amdgcn_mfma_f32_16x16x32_bf16(aL[i][ks], bH[jj], acc[i][jj], 0, 0, 0);
                }
        }

        #pragma unroll
        for (int i = 0; i < 2; ++i)
            #pragma unroll
            for (int rr = 0; rr < 4; ++rr) {
                if constexpr (PASS == 1) {
                    float tm = -INFINITY;
                    #pragma unroll
                    for (int jj = 0; jj < 4; ++jj) {
                        acc[i][jj][rr] *= 0.125f;
                        tm = fmaxf(tm, acc[i][jj][rr]);
                    }
                    tm = fmaxf(tm, __shfl_xor(tm, 1));
                    tm = fmaxf(tm, __shfl_xor(tm, 2));
                    tm = fmaxf(tm, __shfl_xor(tm, 4));
                    tm = fmaxf(tm, __shfl_xor(tm, 8));
                    float mn = fmaxf(m_st[i][rr], tm);
                    float ps = 0.f;
                    #pragma unroll
                    for (int jj = 0; jj < 4; ++jj) ps += __expf(acc[i][jj][rr] - mn);
                    ps += __shfl_xor(ps, 1);
                    ps += __shfl_xor(ps, 2);
                    ps += __shfl_xor(ps, 4);
                    ps += __shfl_xor(ps, 8);
                    l_st[i][rr] = l_st[i][rr]*__expf(m_st[i][rr] - mn) + ps;
                    m_st[i][rr] = mn;
                } else {
                    int row = i0 + w*32 + i*16 + lq*4 + rr;
                    #pragma unroll
                    for (int jj = 0; jj < 4; ++jj) {
                        float p = __expf(acc[i][jj][rr]*0.125f - m_st[i][rr]) * l_st[i][rr];
                        attn[zbase + (size_t)row*SQ + j0 + jj*16 + lrow] = p;
                        qbuf[(w*32 + i*16 + lq*4 + rr)*LSTR + jj*16 + lrow] = f2bf(p);
                    }
                }
            }

        if constexpr (PASS == 2) {
            __syncthreads();
            #pragma unroll
            for (int ks = 0; ks < 2; ++ks) {
                bf16x8 ap[2], bv[4];
                #pragma unroll
                for (int i = 0; i < 2; ++i)
                    ap[i] = *(const bf16x8*)(qbuf + (w*32 + i*16 + lrow)*LSTR + ks*32 + lq*8);
                #pragma unroll
                for (int nd = 0; nd < 4; ++nd)
                    bv[nd] = *(const bf16x8*)(vbuf + (nd*16 + lrow)*LSTR + ks*32 + lq*8);
                #pragma unroll
                for (int i = 0; i < 2; ++i)
                    #pragma unroll
                    for (int nd = 0; nd < 4; ++nd)
                        oa[i][nd] = __builtin_amdgcn_mfma_f32_16x16x32_bf16(ap[i], bv[nd], oa[i][nd], 0, 0, 0);
            }
        }
    }

    if constexpr (PASS == 1) {
        if (lrow == 0) {
            #pragma unroll
            for (int i = 0; i < 2; ++i)
                #pragma unroll
                for (int rr = 0; rr < 4; ++rr) {
                    int row = i0 + w*32 + i*16 + lq*4 + rr;
                    ml[(size_t)z*SQ + row] = m_st[i][rr];
                    ml[(size_t)NB*NH*SQ + (size_t)z*SQ + row] = l_st[i][rr];
                }
        }
    } else {
        #pragma unroll
        for (int i = 0; i < 2; ++i)
            #pragma unroll
            for (int rr = 0; rr < 4; ++rr) {
                int row = i0 + w*32 + i*16 + lq*4 + rr;
                #pragma unroll
                for (int nd = 0; nd < 4; ++nd)
                    AO[(size_t)(b*SQ + row)*EMB + h*HD + nd*16 + lrow] = f2bf(oa[i][nd][rr]);
            }
    }
}

// ---------------------------------------------------------------------------
extern "C" void kernel_launch(void* const* d_in, const int* in_sizes, int n_in,
                              void* d_out, int out_size, void* d_ws, size_t ws_size,
                              hipStream_t stream)
{
    const float* hs   = (const float*)d_in[0];
    const int*   q_qw = (const int*)  d_in[1];
    const float* q_sc = (const float*)d_in[2];
    const float* q_zp = (const float*)d_in[3];
    const float* q_b  = (const float*)d_in[4];
    const int*   k_qw = (const int*)  d_in[5];
    const float* k_sc = (const float*)d_in[6];
    const float* k_zp = (const float*)d_in[7];
    const float* k_b  = (const float*)d_in[8];
    const int*   v_qw = (const int*)  d_in[9];
    const float* v_sc = (const float*)d_in[10];
    const float* v_zp = (const float*)d_in[11];
    const float* v_b  = (const float*)d_in[12];
    const int*   o_qw = (const int*)  d_in[13];
    const float* o_sc = (const float*)d_in[14];
    const float* o_zp = (const float*)d_in[15];
    const float* o_b  = (const float*)d_in[16];

    float* out  = (float*)d_out;
    float* attn = out + OUT0;

    // ws layout (60.5 MB <= 64 MB):
    //   ml: 2*65536 f32 | Wh: 4MW | Wl: 2MW (q,k) | Xh (->AO) | Xl (->Vt)
    //   | Qh | Ql | Kh | Kl        (all 4M shorts)
    const size_t WSZ = (size_t)EMB*EMB;
    const size_t TSZ = (size_t)BSQ*EMB;
    float* ml = (float*)d_ws;
    short* Wh = (short*)(ml + 2*(size_t)NB*NH*SQ);
    short* Wl = Wh + 4*WSZ;
    short* Xh = Wl + 2*WSZ;
    short* Xl = Xh + TSZ;
    short* Qh = Xl + TSZ;
    short* Ql = Qh + TSZ;
    short* Kh = Ql + TSZ;
    short* Kl = Kh + TSZ;
    short* Vt = Xl;   // overlay: Xl dead after K projection
    short* AO = Xh;   // overlay: Xh dead after V projection

    dim3 blk(256);

    prep_w<<<dim3(512, 1, 4), blk, 0, stream>>>(
        q_qw, q_sc, q_zp, k_qw, k_sc, k_zp,
        v_qw, v_sc, v_zp, o_qw, o_sc, o_zp, Wh, Wl);
    prep_x<<<dim3(2048), blk, 0, stream>>>(hs, Xh, Xl);

    k_proj<3,0><<<dim3(8,32), blk, 0, stream>>>(Xh, Xl, Wh,       Wl,       q_b, Qh, Ql, nullptr);
    k_proj<3,0><<<dim3(8,32), blk, 0, stream>>>(Xh, Xl, Wh + WSZ, Wl + WSZ, k_b, Kh, Kl, nullptr);
    k_proj<1,3><<<dim3(8,32), blk, 0, stream>>>(Xh, nullptr, Wh + 2*WSZ, nullptr, v_b, Vt, nullptr, nullptr);

    k_attn<1><<<dim3(16,32), blk, 0, stream>>>(Qh, Ql, Kh, Kl, nullptr, ml, nullptr, nullptr);
    k_attn<2><<<dim3(16,32), blk, 0, stream>>>(Qh, Ql, Kh, Kl, Vt, ml, attn, AO);

    k_proj<1,2><<<dim3(8,32), blk, 0, stream>>>(AO, nullptr, Wh + 3*WSZ, nullptr, o_b, nullptr, nullptr, out);
}

// Round 6
// 820.835 us; speedup vs baseline: 2.0054x; 1.0942x over previous
//
#include <hip/hip_runtime.h>
#include <math.h>

#define EMB 1024
#define NH 16
#define HD 64
#define NB 2
#define SQ 2048
#define BSQ (NB*SQ)
#define NG 16
#define OUT0 ((size_t)BSQ*EMB)

typedef __attribute__((ext_vector_type(8))) short bf16x8;
typedef __attribute__((ext_vector_type(4))) float f32x4;

__device__ __forceinline__ short f2bf(float x){
    unsigned u = __float_as_uint(x);
    u += 0x7fff + ((u >> 16) & 1);     // RNE
    return (short)(u >> 16);
}
__device__ __forceinline__ float bf2f(short h){
    return __uint_as_float(((unsigned)(unsigned short)h) << 16);
}

// ---------------------------------------------------------------------------
// fused prep: z<4 -> dequant weight quadrant z (hi always, lo for q,k);
//             z>=4 -> split X quarter (z-4) into bf16 hi/lo
// grid (512, 1, 8) x 256 threads, 8 elements per thread
// ---------------------------------------------------------------------------
__global__ __launch_bounds__(256) void k_prep(
        const float* __restrict__ hs,
        const int* qq, const float* qs, const float* qz,
        const int* kq, const float* ks, const float* kz,
        const int* vq, const float* vs, const float* vz,
        const int* oq, const float* os, const float* oz,
        short* __restrict__ Wh, short* __restrict__ Wl,
        short* __restrict__ Xh, short* __restrict__ Xl)
{
    int z = blockIdx.z;
    int idx = (blockIdx.x*256 + threadIdx.x)*8;
    alignas(16) short hv[8];
    alignas(16) short lv[8];
    if (z < 4) {
        const int*   qw = z==0?qq : z==1?kq : z==2?vq : oq;
        const float* sc = z==0?qs : z==1?ks : z==2?vs : os;
        const float* zp = z==0?qz : z==1?kz : z==2?vz : oz;
        size_t base = (size_t)z*EMB*EMB;
        int4 a = *(const int4*)(qw + idx);
        int4 b = *(const int4*)(qw + idx + 4);
        int o = idx >> 10, g = (idx & 1023) >> 6;
        float s = sc[o*NG + g], zv = zp[o*NG + g];
        int qv[8] = {a.x,a.y,a.z,a.w,b.x,b.y,b.z,b.w};
        #pragma unroll
        for (int j = 0; j < 8; ++j) {
            float wv = ((float)qv[j] - zv)*s;
            short h = f2bf(wv); hv[j] = h;
            lv[j] = f2bf(wv - bf2f(h));
        }
        *(bf16x8*)(Wh + base + idx) = *(const bf16x8*)hv;
        if (z < 2)
            *(bf16x8*)(Wl + base + idx) = *(const bf16x8*)lv;
    } else {
        size_t off = (size_t)(z - 4)*((size_t)BSQ/4*EMB) + idx;
        float4 a = *(const float4*)(hs + off);
        float4 b = *(const float4*)(hs + off + 4);
        float xv[8] = {a.x,a.y,a.z,a.w,b.x,b.y,b.z,b.w};
        #pragma unroll
        for (int j = 0; j < 8; ++j) {
            short h = f2bf(xv[j]); hv[j] = h;
            lv[j] = f2bf(xv[j] - bf2f(h));
        }
        *(bf16x8*)(Xh + off) = *(const bf16x8*)hv;
        *(bf16x8*)(Xl + off) = *(const bf16x8*)lv;
    }
}

// ---------------------------------------------------------------------------
// bf16 MFMA GEMM body: C[4096,1024] = A[4096,1024] * B[1024,1024]^T + bias
// TERMS=3: hh+hl+lh split.  TERMS=1: plain bf16.
// EPI: 0 = bf16 hi/lo pair; 2 = fp32 (nt); 3 = transposed bf16 -> Vt[z][d][s]
// 128x128 tile, BK=32, 4 waves (2x2).
// ---------------------------------------------------------------------------
template<int TERMS, int EPI>
__device__ __forceinline__ void proj_body(
        const short* __restrict__ Ahg, const short* __restrict__ Alg,
        const short* __restrict__ Bhg, const short* __restrict__ Blg,
        const float* __restrict__ bias,
        short* __restrict__ outH, short* __restrict__ outL,
        float* __restrict__ outF,
        int bx, int by)
{
    constexpr bool SPL = (TERMS > 1);
    constexpr int LSTR = 40;
    constexpr int MSZ  = 128*LSTR*(SPL?2:1);
    constexpr int STAGE = 2*MSZ;
    constexpr int TSH  = (EPI == 3) ? 128*136 : 0;
    constexpr int LDSN = (STAGE > TSH) ? STAGE : TSH;
    __shared__ short lds[LDSN];
    short* As  = lds;
    short* Bs  = lds + MSZ;
    short* Asl = As + 128*LSTR;
    short* Bsl = Bs + 128*LSTR;

    const int tid = threadIdx.x;
    const int l = tid & 63, w = tid >> 6;
    const int lrow = l & 15, lq = l >> 4;
    const int wr = w >> 1, wc = w & 1;
    const int m0 = by*128, n0 = bx*128;
    const int r = tid >> 1, kh = (tid & 1)*16;

    f32x4 acc[4][4] = {};

    for (int k0 = 0; k0 < EMB; k0 += 32) {
        const short* as = Ahg + (size_t)(m0 + r)*EMB + k0 + kh;
        bf16x8 a0 = *(const bf16x8*)as;
        bf16x8 a1 = *(const bf16x8*)(as + 8);
        const short* bs = Bhg + (size_t)(n0 + r)*EMB + k0 + kh;
        bf16x8 b0 = *(const bf16x8*)bs;
        bf16x8 b1 = *(const bf16x8*)(bs + 8);
        bf16x8 a2{}, a3{}, b2{}, b3{};
        if constexpr (SPL) {
            const short* as2 = Alg + (size_t)(m0 + r)*EMB + k0 + kh;
            a2 = *(const bf16x8*)as2; a3 = *(const bf16x8*)(as2 + 8);
            const short* bs2 = Blg + (size_t)(n0 + r)*EMB + k0 + kh;
            b2 = *(const bf16x8*)bs2; b3 = *(const bf16x8*)(bs2 + 8);
        }
        __syncthreads();
        *(bf16x8*)(As + r*LSTR + kh)     = a0;
        *(bf16x8*)(As + r*LSTR + kh + 8) = a1;
        *(bf16x8*)(Bs + r*LSTR + kh)     = b0;
        *(bf16x8*)(Bs + r*LSTR + kh + 8) = b1;
        if constexpr (SPL) {
            *(bf16x8*)(Asl + r*LSTR + kh)     = a2;
            *(bf16x8*)(Asl + r*LSTR + kh + 8) = a3;
            *(bf16x8*)(Bsl + r*LSTR + kh)     = b2;
            *(bf16x8*)(Bsl + r*LSTR + kh + 8) = b3;
        }
        __syncthreads();

        bf16x8 aH[4], aL[4], bH[4], bL[4];
        #pragma unroll
        for (int i = 0; i < 4; ++i) {
            aH[i] = *(const bf16x8*)(As + (wr*64 + i*16 + lrow)*LSTR + lq*8);
            if constexpr (SPL) aL[i] = *(const bf16x8*)(Asl + (wr*64 + i*16 + lrow)*LSTR + lq*8);
        }
        #pragma unroll
        for (int j = 0; j < 4; ++j) {
            bH[j] = *(const bf16x8*)(Bs + (wc*64 + j*16 + lrow)*LSTR + lq*8);
            if constexpr (SPL) bL[j] = *(const bf16x8*)(Bsl + (wc*64 + j*16 + lrow)*LSTR + lq*8);
        }
        #pragma unroll
        for (int i = 0; i < 4; ++i)
            #pragma unroll
            for (int j = 0; j < 4; ++j) {
                acc[i][j] = __builtin_amdgcn_mfma_f32_16x16x32_bf16(aH[i], bH[j], acc[i][j], 0, 0, 0);
                if constexpr (SPL) {
                    acc[i][j] = __builtin_amdgcn_mfma_f32_16x16x32_bf16(aH[i], bL[j], acc[i][j], 0, 0, 0);
                    acc[i][j] = __builtin_amdgcn_mfma_f32_16x16x32_bf16(aL[i], bH[j], acc[i][j], 0, 0, 0);
                }
            }
    }

    if constexpr (EPI == 3) {
        // transpose through LDS, write Vt[z][d][s] coalesced along s
        __syncthreads();
        #pragma unroll
        for (int i = 0; i < 4; ++i) {
            int rl = wr*64 + i*16 + lq*4;
            #pragma unroll
            for (int j = 0; j < 4; ++j) {
                int cl = wc*64 + j*16 + lrow;
                float bv = bias[n0 + cl];
                #pragma unroll
                for (int rr = 0; rr < 4; ++rr)
                    lds[cl*136 + rl + rr] = f2bf(acc[i][j][rr] + bv);
            }
        }
        __syncthreads();
        int c = tid >> 1, hf = (tid & 1)*64;
        int gc = n0 + c;
        int z2 = (m0 >> 11)*16 + (gc >> 6);
        int d = gc & 63;
        short* dst = outH + ((size_t)z2*HD + d)*SQ + (m0 & (SQ-1)) + hf;
        #pragma unroll
        for (int u = 0; u < 8; ++u)
            *(bf16x8*)(dst + u*8) = *(const bf16x8*)(lds + c*136 + hf + u*8);
        return;
    }

    #pragma unroll
    for (int i = 0; i < 4; ++i) {
        int rb = m0 + wr*64 + i*16 + lq*4;
        #pragma unroll
        for (int j = 0; j < 4; ++j) {
            int cb = n0 + wc*64 + j*16 + lrow;
            float bv = bias[cb];
            #pragma unroll
            for (int rr = 0; rr < 4; ++rr) {
                float y = acc[i][j][rr] + bv;
                size_t off = (size_t)(rb + rr)*EMB + cb;
                if constexpr (EPI == 0) {
                    short hh = f2bf(y);
                    outH[off] = hh;
                    outL[off] = f2bf(y - bf2f(hh));
                } else {
                    __builtin_nontemporal_store(y, outF + off);
                }
            }
        }
    }
}

// Q and K projections fused over grid.z
__global__ __launch_bounds__(256, 2) void k_projqk(
        const short* __restrict__ Xh, const short* __restrict__ Xl,
        const short* __restrict__ Wh, const short* __restrict__ Wl,
        const float* bq, const float* bk,
        short* Qh, short* Ql, short* Kh, short* Kl)
{
    const size_t WSZ = (size_t)EMB*EMB;
    int z = blockIdx.z;
    proj_body<3,0>(Xh, Xl, Wh + (size_t)z*WSZ, Wl + (size_t)z*WSZ,
                   z ? bk : bq, z ? Kh : Qh, z ? Kl : Ql, nullptr,
                   blockIdx.x, blockIdx.y);
}

__global__ __launch_bounds__(256, 2) void k_projv(
        const short* __restrict__ Xh, const short* __restrict__ Wh,
        const float* bv, short* Vt)
{
    proj_body<1,3>(Xh, nullptr, Wh, nullptr, bv, Vt, nullptr, nullptr,
                   blockIdx.x, blockIdx.y);
}

__global__ __launch_bounds__(256, 2) void k_projo(
        const short* __restrict__ AO, const short* __restrict__ Wh,
        const float* bo, float* out)
{
    proj_body<1,2>(AO, nullptr, Wh, nullptr, bo, nullptr, nullptr, out,
                   blockIdx.x, blockIdx.y);
}

// ---------------------------------------------------------------------------
// attention, two passes over an identical score computation.
// PASS1: lane-local online (m,l), one cross-lane merge at end -> ml.
// PASS2: normalized P write (nt) + P*V.
// ---------------------------------------------------------------------------
template<int PASS>
__global__ __launch_bounds__(256, 2) void k_attn(
        const short* __restrict__ Qh, const short* __restrict__ Ql,
        const short* __restrict__ Kh, const short* __restrict__ Kl,
        const short* __restrict__ Vt,
        float* __restrict__ ml,
        float* __restrict__ attn,
        short* __restrict__ AO)
{
    constexpr int LSTR = 72;                 // 64 + 8 pad
    __shared__ short qbuf[128*LSTR*2];       // hi | lo ; hi half reused as P tile in PASS2
    __shared__ short kbuf[64*LSTR*2];        // hi | lo
    __shared__ short vbuf[(PASS==2) ? 64*LSTR : 8];
    constexpr int QOFF = 128*LSTR;
    constexpr int KOFF = 64*LSTR;

    const int tid = threadIdx.x;
    const int l = tid & 63, w = tid >> 6;
    const int lrow = l & 15, lq = l >> 4;
    const int z = blockIdx.y, b = z >> 4, h = z & 15;
    const int i0 = blockIdx.x*128;
    const size_t qrow0 = (size_t)(b*SQ + i0);
    const size_t zbase = (size_t)z*SQ*SQ;

    {
        int rr = tid >> 1, kh2 = (tid & 1)*32;
        const short* qh = Qh + (qrow0 + rr)*EMB + h*HD + kh2;
        const short* ql = Ql + (qrow0 + rr)*EMB + h*HD + kh2;
        #pragma unroll
        for (int u = 0; u < 4; ++u) {
            *(bf16x8*)(qbuf + rr*LSTR + kh2 + u*8)        = *(const bf16x8*)(qh + u*8);
            *(bf16x8*)(qbuf + QOFF + rr*LSTR + kh2 + u*8) = *(const bf16x8*)(ql + u*8);
        }
    }
    __syncthreads();
    bf16x8 aH[2][2], aL[2][2];
    #pragma unroll
    for (int i = 0; i < 2; ++i)
        #pragma unroll
        for (int ks = 0; ks < 2; ++ks) {
            aH[i][ks] = *(const bf16x8*)(qbuf + (w*32 + i*16 + lrow)*LSTR + ks*32 + lq*8);
            aL[i][ks] = *(const bf16x8*)(qbuf + QOFF + (w*32 + i*16 + lrow)*LSTR + ks*32 + lq*8);
        }

    // PASS1: lane-local running (m, l) over this lane's 4 columns per tile.
    // PASS2: final per-row m and 1/l loaded from ml.
    float m_st[2][4], l_st[2][4];
    #pragma unroll
    for (int i = 0; i < 2; ++i)
        #pragma unroll
        for (int rr = 0; rr < 4; ++rr) {
            if constexpr (PASS == 1) {
                m_st[i][rr] = -INFINITY; l_st[i][rr] = 0.f;
            } else {
                int row = i0 + w*32 + i*16 + lq*4 + rr;
                m_st[i][rr] = ml[(size_t)z*SQ + row];
                l_st[i][rr] = 1.0f / ml[(size_t)NB*NH*SQ + (size_t)z*SQ + row];
            }
        }

    f32x4 oa[2][4] = {};

    for (int j0 = 0; j0 < SQ; j0 += 64) {
        // stage K (hi/lo) and V: 64 rows x 64 shorts; 4 threads/row x 16 shorts
        int c = tid >> 2, kh2 = (tid & 3)*16;
        const short* khp = Kh + (size_t)(b*SQ + j0 + c)*EMB + h*HD + kh2;
        const short* klp = Kl + (size_t)(b*SQ + j0 + c)*EMB + h*HD + kh2;
        bf16x8 k0a = *(const bf16x8*)khp;
        bf16x8 k0b = *(const bf16x8*)(khp + 8);
        bf16x8 k1a = *(const bf16x8*)klp;
        bf16x8 k1b = *(const bf16x8*)(klp + 8);
        bf16x8 va{}, vb{};
        if constexpr (PASS == 2) {
            const short* vp = Vt + ((size_t)z*HD + c)*SQ + j0 + kh2;
            va = *(const bf16x8*)vp;
            vb = *(const bf16x8*)(vp + 8);
        }
        __syncthreads();
        *(bf16x8*)(kbuf + c*LSTR + kh2)            = k0a;
        *(bf16x8*)(kbuf + c*LSTR + kh2 + 8)        = k0b;
        *(bf16x8*)(kbuf + KOFF + c*LSTR + kh2)     = k1a;
        *(bf16x8*)(kbuf + KOFF + c*LSTR + kh2 + 8) = k1b;
        if constexpr (PASS == 2) {
            *(bf16x8*)(vbuf + c*LSTR + kh2)     = va;
            *(bf16x8*)(vbuf + c*LSTR + kh2 + 8) = vb;
        }
        __syncthreads();

        f32x4 acc[2][4] = {};
        #pragma unroll
        for (int ks = 0; ks < 2; ++ks) {
            bf16x8 bH[4], bL[4];
            #pragma unroll
            for (int jj = 0; jj < 4; ++jj) {
                bH[jj] = *(const bf16x8*)(kbuf + (jj*16 + lrow)*LSTR + ks*32 + lq*8);
                bL[jj] = *(const bf16x8*)(kbuf + KOFF + (jj*16 + lrow)*LSTR + ks*32 + lq*8);
            }
            #pragma unroll
            for (int i = 0; i < 2; ++i)
                #pragma unroll
                for (int jj = 0; jj < 4; ++jj) {
                    acc[i][jj] = __builtin_amdgcn_mfma_f32_16x16x32_bf16(aH[i][ks], bH[jj], acc[i][jj], 0, 0, 0);
                    acc[i][jj] = __builtin_amdgcn_mfma_f32_16x16x32_bf16(aH[i][ks], bL[jj], acc[i][jj], 0, 0, 0);
                    acc[i][jj] = __builtin_amdgcn_mfma_f32_16x16x32_bf16(aL[i][ks], bH[jj], acc[i][jj], 0, 0, 0);
                }
        }

        #pragma unroll
        for (int i = 0; i < 2; ++i)
            #pragma unroll
            for (int rr = 0; rr < 4; ++rr) {
                if constexpr (PASS == 1) {
                    // lane-local online update over this lane's 4 columns
                    float s0 = acc[i][0][rr]*0.125f;
                    float s1 = acc[i][1][rr]*0.125f;
                    float s2 = acc[i][2][rr]*0.125f;
                    float s3 = acc[i][3][rr]*0.125f;
                    float tm = fmaxf(fmaxf(s0, s1), fmaxf(s2, s3));
                    float mo = m_st[i][rr];
                    float mn = fmaxf(mo, tm);
                    l_st[i][rr] = l_st[i][rr]*__expf(mo - mn)
                                + __expf(s0 - mn) + __expf(s1 - mn)
                                + __expf(s2 - mn) + __expf(s3 - mn);
                    m_st[i][rr] = mn;
                } else {
                    int row = i0 + w*32 + i*16 + lq*4 + rr;
                    #pragma unroll
                    for (int jj = 0; jj < 4; ++jj) {
                        float p = __expf(acc[i][jj][rr]*0.125f - m_st[i][rr]) * l_st[i][rr];
                        __builtin_nontemporal_store(p, attn + zbase + (size_t)row*SQ + j0 + jj*16 + lrow);
                        qbuf[(w*32 + i*16 + lq*4 + rr)*LSTR + jj*16 + lrow] = f2bf(p);
                    }
                }
            }

        if constexpr (PASS == 2) {
            // no barrier: P round-trip is wave-private (rows w*32..w*32+31)
            #pragma unroll
            for (int ks = 0; ks < 2; ++ks) {
                bf16x8 ap[2], bv[4];
                #pragma unroll
                for (int i = 0; i < 2; ++i)
                    ap[i] = *(const bf16x8*)(qbuf + (w*32 + i*16 + lrow)*LSTR + ks*32 + lq*8);
                #pragma unroll
                for (int nd = 0; nd < 4; ++nd)
                    bv[nd] = *(const bf16x8*)(vbuf + (nd*16 + lrow)*LSTR + ks*32 + lq*8);
                #pragma unroll
                for (int i = 0; i < 2; ++i)
                    #pragma unroll
                    for (int nd = 0; nd < 4; ++nd)
                        oa[i][nd] = __builtin_amdgcn_mfma_f32_16x16x32_bf16(ap[i], bv[nd], oa[i][nd], 0, 0, 0);
            }
        }
    }

    if constexpr (PASS == 1) {
        // cross-lane merge of 16 lane-partials per row, once
        #pragma unroll
        for (int i = 0; i < 2; ++i)
            #pragma unroll
            for (int rr = 0; rr < 4; ++rr) {
                float m = m_st[i][rr], lv = l_st[i][rr];
                #pragma unroll
                for (int off = 1; off < 16; off <<= 1) {
                    float m2 = __shfl_xor(m, off);
                    float l2 = __shfl_xor(lv, off);
                    float mn = fmaxf(m, m2);
                    lv = lv*__expf(m - mn) + l2*__expf(m2 - mn);
                    m = mn;
                }
                if (lrow == 0) {
                    int row = i0 + w*32 + i*16 + lq*4 + rr;
                    ml[(size_t)z*SQ + row] = m;
                    ml[(size_t)NB*NH*SQ + (size_t)z*SQ + row] = lv;
                }
            }
    } else {
        #pragma unroll
        for (int i = 0; i < 2; ++i)
            #pragma unroll
            for (int rr = 0; rr < 4; ++rr) {
                int row = i0 + w*32 + i*16 + lq*4 + rr;
                #pragma unroll
                for (int nd = 0; nd < 4; ++nd)
                    AO[(size_t)(b*SQ + row)*EMB + h*HD + nd*16 + lrow] = f2bf(oa[i][nd][rr]);
            }
    }
}

// ---------------------------------------------------------------------------
extern "C" void kernel_launch(void* const* d_in, const int* in_sizes, int n_in,
                              void* d_out, int out_size, void* d_ws, size_t ws_size,
                              hipStream_t stream)
{
    const float* hs   = (const float*)d_in[0];
    const int*   q_qw = (const int*)  d_in[1];
    const float* q_sc = (const float*)d_in[2];
    const float* q_zp = (const float*)d_in[3];
    const float* q_b  = (const float*)d_in[4];
    const int*   k_qw = (const int*)  d_in[5];
    const float* k_sc = (const float*)d_in[6];
    const float* k_zp = (const float*)d_in[7];
    const float* k_b  = (const float*)d_in[8];
    const int*   v_qw = (const int*)  d_in[9];
    const float* v_sc = (const float*)d_in[10];
    const float* v_zp = (const float*)d_in[11];
    const float* v_b  = (const float*)d_in[12];
    const int*   o_qw = (const int*)  d_in[13];
    const float* o_sc = (const float*)d_in[14];
    const float* o_zp = (const float*)d_in[15];
    const float* o_b  = (const float*)d_in[16];

    float* out  = (float*)d_out;
    float* attn = out + OUT0;

    // ws layout (60.5 MB <= 64 MB):
    //   ml: 2*65536 f32 | Wh: 4MW | Wl: 2MW (q,k) | Xh (->AO) | Xl (->Vt)
    //   | Qh | Ql | Kh | Kl        (all 4M shorts)
    const size_t WSZ = (size_t)EMB*EMB;
    const size_t TSZ = (size_t)BSQ*EMB;
    float* ml = (float*)d_ws;
    short* Wh = (short*)(ml + 2*(size_t)NB*NH*SQ);
    short* Wl = Wh + 4*WSZ;
    short* Xh = Wl + 2*WSZ;
    short* Xl = Xh + TSZ;
    short* Qh = Xl + TSZ;
    short* Ql = Qh + TSZ;
    short* Kh = Ql + TSZ;
    short* Kl = Kh + TSZ;
    short* Vt = Xl;   // overlay: Xl dead after K projection
    short* AO = Xh;   // overlay: Xh dead after V projection

    dim3 blk(256);

    k_prep<<<dim3(512, 1, 8), blk, 0, stream>>>(
        hs,
        q_qw, q_sc, q_zp, k_qw, k_sc, k_zp,
        v_qw, v_sc, v_zp, o_qw, o_sc, o_zp,
        Wh, Wl, Xh, Xl);

    k_projqk<<<dim3(8, 32, 2), blk, 0, stream>>>(
        Xh, Xl, Wh, Wl, q_b, k_b, Qh, Ql, Kh, Kl);

    k_projv<<<dim3(8, 32), blk, 0, stream>>>(Xh, Wh + 2*WSZ, v_b, Vt);

    k_attn<1><<<dim3(16, 32), blk, 0, stream>>>(Qh, Ql, Kh, Kl, nullptr, ml, nullptr, nullptr);
    k_attn<2><<<dim3(16, 32), blk, 0, stream>>>(Qh, Ql, Kh, Kl, Vt, ml, attn, AO);

    k_projo<<<dim3(8, 32), blk, 0, stream>>>(AO, Wh + 3*WSZ, o_b, out);
}

// Round 8
// 793.897 us; speedup vs baseline: 2.0734x; 1.0339x over previous
//
#include <hip/hip_runtime.h>
#include <math.h>

#define EMB 1024
#define NH 16
#define HD 64
#define NB 2
#define SQ 2048
#define BSQ (NB*SQ)
#define NG 16
#define OUT0 ((size_t)BSQ*EMB)

typedef __attribute__((ext_vector_type(8))) short bf16x8;
typedef __attribute__((ext_vector_type(4))) float f32x4;

__device__ __forceinline__ short f2bf(float x){
    unsigned u = __float_as_uint(x);
    u += 0x7fff + ((u >> 16) & 1);     // RNE
    return (short)(u >> 16);
}
__device__ __forceinline__ float bf2f(short h){
    return __uint_as_float(((unsigned)(unsigned short)h) << 16);
}

// ---------------------------------------------------------------------------
// fused prep: z<4 -> dequant weight quadrant z (hi always, lo for q,k);
//             z>=4 -> split X quarter (z-4) into bf16 hi/lo
// ---------------------------------------------------------------------------
__global__ __launch_bounds__(256) void k_prep(
        const float* __restrict__ hs,
        const int* qq, const float* qs, const float* qz,
        const int* kq, const float* ks, const float* kz,
        const int* vq, const float* vs, const float* vz,
        const int* oq, const float* os, const float* oz,
        short* __restrict__ Wh, short* __restrict__ Wl,
        short* __restrict__ Xh, short* __restrict__ Xl)
{
    int z = blockIdx.z;
    int idx = (blockIdx.x*256 + threadIdx.x)*8;
    alignas(16) short hv[8];
    alignas(16) short lv[8];
    if (z < 4) {
        const int*   qw = z==0?qq : z==1?kq : z==2?vq : oq;
        const float* sc = z==0?qs : z==1?ks : z==2?vs : os;
        const float* zp = z==0?qz : z==1?kz : z==2?vz : oz;
        size_t base = (size_t)z*EMB*EMB;
        int4 a = *(const int4*)(qw + idx);
        int4 b = *(const int4*)(qw + idx + 4);
        int o = idx >> 10, g = (idx & 1023) >> 6;
        float s = sc[o*NG + g], zv = zp[o*NG + g];
        int qv[8] = {a.x,a.y,a.z,a.w,b.x,b.y,b.z,b.w};
        #pragma unroll
        for (int j = 0; j < 8; ++j) {
            float wv = ((float)qv[j] - zv)*s;
            short h = f2bf(wv); hv[j] = h;
            lv[j] = f2bf(wv - bf2f(h));
        }
        *(bf16x8*)(Wh + base + idx) = *(const bf16x8*)hv;
        if (z < 2)
            *(bf16x8*)(Wl + base + idx) = *(const bf16x8*)lv;
    } else {
        size_t off = (size_t)(z - 4)*((size_t)BSQ/4*EMB) + idx;
        float4 a = *(const float4*)(hs + off);
        float4 b = *(const float4*)(hs + off + 4);
        float xv[8] = {a.x,a.y,a.z,a.w,b.x,b.y,b.z,b.w};
        #pragma unroll
        for (int j = 0; j < 8; ++j) {
            short h = f2bf(xv[j]); hv[j] = h;
            lv[j] = f2bf(xv[j] - bf2f(h));
        }
        *(bf16x8*)(Xh + off) = *(const bf16x8*)hv;
        *(bf16x8*)(Xl + off) = *(const bf16x8*)lv;
    }
}

// ---------------------------------------------------------------------------
// bf16 MFMA GEMM body: C[4096,1024] = A[4096,1024] * B[1024,1024]^T + bias
// TERMS=3: hh+hl+lh split.  TERMS=1: plain bf16.
// EPI: 0 = bf16 hi/lo pair; 2 = fp32 (nt); 3 = transposed bf16 -> Vt[z][d][s]
// 128x128 tile, BK=32, 4 waves (2x2).
// ---------------------------------------------------------------------------
template<int TERMS, int EPI>
__device__ __forceinline__ void proj_body(
        const short* __restrict__ Ahg, const short* __restrict__ Alg,
        const short* __restrict__ Bhg, const short* __restrict__ Blg,
        const float* __restrict__ bias,
        short* __restrict__ outH, short* __restrict__ outL,
        float* __restrict__ outF,
        int bx, int by)
{
    constexpr bool SPL = (TERMS > 1);
    constexpr int LSTR = 40;
    constexpr int MSZ  = 128*LSTR*(SPL?2:1);
    constexpr int STAGE = 2*MSZ;
    constexpr int TSH  = (EPI == 3) ? 128*136 : 0;
    constexpr int LDSN = (STAGE > TSH) ? STAGE : TSH;
    __shared__ short lds[LDSN];
    short* As  = lds;
    short* Bs  = lds + MSZ;
    short* Asl = As + 128*LSTR;
    short* Bsl = Bs + 128*LSTR;

    const int tid = threadIdx.x;
    const int l = tid & 63, w = tid >> 6;
    const int lrow = l & 15, lq = l >> 4;
    const int wr = w >> 1, wc = w & 1;
    const int m0 = by*128, n0 = bx*128;
    const int r = tid >> 1, kh = (tid & 1)*16;

    f32x4 acc[4][4] = {};

    for (int k0 = 0; k0 < EMB; k0 += 32) {
        const short* as = Ahg + (size_t)(m0 + r)*EMB + k0 + kh;
        bf16x8 a0 = *(const bf16x8*)as;
        bf16x8 a1 = *(const bf16x8*)(as + 8);
        const short* bs = Bhg + (size_t)(n0 + r)*EMB + k0 + kh;
        bf16x8 b0 = *(const bf16x8*)bs;
        bf16x8 b1 = *(const bf16x8*)(bs + 8);
        bf16x8 a2{}, a3{}, b2{}, b3{};
        if constexpr (SPL) {
            const short* as2 = Alg + (size_t)(m0 + r)*EMB + k0 + kh;
            a2 = *(const bf16x8*)as2; a3 = *(const bf16x8*)(as2 + 8);
            const short* bs2 = Blg + (size_t)(n0 + r)*EMB + k0 + kh;
            b2 = *(const bf16x8*)bs2; b3 = *(const bf16x8*)(bs2 + 8);
        }
        __syncthreads();
        *(bf16x8*)(As + r*LSTR + kh)     = a0;
        *(bf16x8*)(As + r*LSTR + kh + 8) = a1;
        *(bf16x8*)(Bs + r*LSTR + kh)     = b0;
        *(bf16x8*)(Bs + r*LSTR + kh + 8) = b1;
        if constexpr (SPL) {
            *(bf16x8*)(Asl + r*LSTR + kh)     = a2;
            *(bf16x8*)(Asl + r*LSTR + kh + 8) = a3;
            *(bf16x8*)(Bsl + r*LSTR + kh)     = b2;
            *(bf16x8*)(Bsl + r*LSTR + kh + 8) = b3;
        }
        __syncthreads();

        bf16x8 aH[4], aL[4], bH[4], bL[4];
        #pragma unroll
        for (int i = 0; i < 4; ++i) {
            aH[i] = *(const bf16x8*)(As + (wr*64 + i*16 + lrow)*LSTR + lq*8);
            if constexpr (SPL) aL[i] = *(const bf16x8*)(Asl + (wr*64 + i*16 + lrow)*LSTR + lq*8);
        }
        #pragma unroll
        for (int j = 0; j < 4; ++j) {
            bH[j] = *(const bf16x8*)(Bs + (wc*64 + j*16 + lrow)*LSTR + lq*8);
            if constexpr (SPL) bL[j] = *(const bf16x8*)(Bsl + (wc*64 + j*16 + lrow)*LSTR + lq*8);
        }
        #pragma unroll
        for (int i = 0; i < 4; ++i)
            #pragma unroll
            for (int j = 0; j < 4; ++j) {
                acc[i][j] = __builtin_amdgcn_mfma_f32_16x16x32_bf16(aH[i], bH[j], acc[i][j], 0, 0, 0);
                if constexpr (SPL) {
                    acc[i][j] = __builtin_amdgcn_mfma_f32_16x16x32_bf16(aH[i], bL[j], acc[i][j], 0, 0, 0);
                    acc[i][j] = __builtin_amdgcn_mfma_f32_16x16x32_bf16(aL[i], bH[j], acc[i][j], 0, 0, 0);
                }
            }
    }

    if constexpr (EPI == 3) {
        // transpose through LDS, write Vt[z][d][s] coalesced along s
        __syncthreads();
        #pragma unroll
        for (int i = 0; i < 4; ++i) {
            int rl = wr*64 + i*16 + lq*4;
            #pragma unroll
            for (int j = 0; j < 4; ++j) {
                int cl = wc*64 + j*16 + lrow;
                float bv = bias[n0 + cl];
                #pragma unroll
                for (int rr = 0; rr < 4; ++rr)
                    lds[cl*136 + rl + rr] = f2bf(acc[i][j][rr] + bv);
            }
        }
        __syncthreads();
        int c = tid >> 1, hf = (tid & 1)*64;
        int gc = n0 + c;
        int z2 = (m0 >> 11)*16 + (gc >> 6);
        int d = gc & 63;
        short* dst = outH + ((size_t)z2*HD + d)*SQ + (m0 & (SQ-1)) + hf;
        #pragma unroll
        for (int u = 0; u < 8; ++u)
            *(bf16x8*)(dst + u*8) = *(const bf16x8*)(lds + c*136 + hf + u*8);
        return;
    }

    #pragma unroll
    for (int i = 0; i < 4; ++i) {
        int rb = m0 + wr*64 + i*16 + lq*4;
        #pragma unroll
        for (int j = 0; j < 4; ++j) {
            int cb = n0 + wc*64 + j*16 + lrow;
            float bv = bias[cb];
            #pragma unroll
            for (int rr = 0; rr < 4; ++rr) {
                float y = acc[i][j][rr] + bv;
                size_t off = (size_t)(rb + rr)*EMB + cb;
                if constexpr (EPI == 0) {
                    short hh = f2bf(y);
                    outH[off] = hh;
                    outL[off] = f2bf(y - bf2f(hh));
                } else {
                    __builtin_nontemporal_store(y, outF + off);
                }
            }
        }
    }
}

// Q, K (3-term, hi/lo out) and V (1-term, transposed out) fused over grid.z
__global__ __launch_bounds__(256, 2) void k_projqkv(
        const short* __restrict__ Xh, const short* __restrict__ Xl,
        const short* __restrict__ Wh, const short* __restrict__ Wl,
        const float* bq, const float* bk, const float* bv,
        short* Qh, short* Ql, short* Kh, short* Kl, short* Vt)
{
    const size_t WSZ = (size_t)EMB*EMB;
    int z = blockIdx.z;
    if (z < 2)
        proj_body<3,0>(Xh, Xl, Wh + (size_t)z*WSZ, Wl + (size_t)z*WSZ,
                       z ? bk : bq, z ? Kh : Qh, z ? Kl : Ql, nullptr,
                       blockIdx.x, blockIdx.y);
    else
        proj_body<1,3>(Xh, nullptr, Wh + 2*WSZ, nullptr, bv, Vt, nullptr, nullptr,
                       blockIdx.x, blockIdx.y);
}

__global__ __launch_bounds__(256, 2) void k_projo(
        const short* __restrict__ AO, const short* __restrict__ Wh,
        const float* bo, float* out)
{
    proj_body<1,2>(AO, nullptr, Wh, nullptr, bo, nullptr, nullptr, out,
                   blockIdx.x, blockIdx.y);
}

// ---------------------------------------------------------------------------
// attention, two passes over an identical score computation.
// PASS1: lane-local online (m,l), one cross-lane merge at end -> ml.
// PASS2: P (bf16) -> LDS -> wide coalesced fp32 attn write + P*V.
// Q staged hi then lo through ONE 128xLSTR buffer (halves LDS).
// ---------------------------------------------------------------------------
template<int PASS>
__global__ __launch_bounds__(256, (PASS==1) ? 3 : 2) void k_attn(
        const short* __restrict__ Qh, const short* __restrict__ Ql,
        const short* __restrict__ Kh, const short* __restrict__ Kl,
        const short* __restrict__ Vt,
        float* __restrict__ ml,
        float* __restrict__ attn,
        short* __restrict__ AO)
{
    constexpr int LSTR = 72;                 // 64 + 8 pad
    __shared__ short qbuf[128*LSTR];         // Q hi then lo staging; P tile in PASS2
    __shared__ short kbuf[64*LSTR*2];        // hi | lo
    __shared__ short vbuf[(PASS==2) ? 64*LSTR : 8];
    constexpr int KOFF = 64*LSTR;

    const int tid = threadIdx.x;
    const int l = tid & 63, w = tid >> 6;
    const int lrow = l & 15, lq = l >> 4;
    const int z = blockIdx.y, b = z >> 4, h = z & 15;
    const int i0 = blockIdx.x*128;
    const size_t qrow0 = (size_t)(b*SQ + i0);
    const size_t zbase = (size_t)z*SQ*SQ;

    const int rs = tid >> 1, kh0 = (tid & 1)*32;
    bf16x8 aH[2][2], aL[2][2];
    {
        const short* qh = Qh + (qrow0 + rs)*EMB + h*HD + kh0;
        #pragma unroll
        for (int u = 0; u < 4; ++u)
            *(bf16x8*)(qbuf + rs*LSTR + kh0 + u*8) = *(const bf16x8*)(qh + u*8);
        __syncthreads();
        #pragma unroll
        for (int i = 0; i < 2; ++i)
            #pragma unroll
            for (int ks = 0; ks < 2; ++ks)
                aH[i][ks] = *(const bf16x8*)(qbuf + (w*32 + i*16 + lrow)*LSTR + ks*32 + lq*8);
        __syncthreads();
        const short* ql = Ql + (qrow0 + rs)*EMB + h*HD + kh0;
        #pragma unroll
        for (int u = 0; u < 4; ++u)
            *(bf16x8*)(qbuf + rs*LSTR + kh0 + u*8) = *(const bf16x8*)(ql + u*8);
        __syncthreads();
        #pragma unroll
        for (int i = 0; i < 2; ++i)
            #pragma unroll
            for (int ks = 0; ks < 2; ++ks)
                aL[i][ks] = *(const bf16x8*)(qbuf + (w*32 + i*16 + lrow)*LSTR + ks*32 + lq*8);
    }

    float m_st[2][4], l_st[2][4];
    #pragma unroll
    for (int i = 0; i < 2; ++i)
        #pragma unroll
        for (int rr = 0; rr < 4; ++rr) {
            if constexpr (PASS == 1) {
                m_st[i][rr] = -INFINITY; l_st[i][rr] = 0.f;
            } else {
                int row = i0 + w*32 + i*16 + lq*4 + rr;
                m_st[i][rr] = ml[(size_t)z*SQ + row];
                l_st[i][rr] = 1.0f / ml[(size_t)NB*NH*SQ + (size_t)z*SQ + row];
            }
        }

    f32x4 oa[2][4] = {};

    for (int j0 = 0; j0 < SQ; j0 += 64) {
        int c = tid >> 2, kh2 = (tid & 3)*16;
        const short* khp = Kh + (size_t)(b*SQ + j0 + c)*EMB + h*HD + kh2;
        const short* klp = Kl + (size_t)(b*SQ + j0 + c)*EMB + h*HD + kh2;
        bf16x8 k0a = *(const bf16x8*)khp;
        bf16x8 k0b = *(const bf16x8*)(khp + 8);
        bf16x8 k1a = *(const bf16x8*)klp;
        bf16x8 k1b = *(const bf16x8*)(klp + 8);
        bf16x8 va{}, vb{};
        if constexpr (PASS == 2) {
            const short* vp = Vt + ((size_t)z*HD + c)*SQ + j0 + kh2;
            va = *(const bf16x8*)vp;
            vb = *(const bf16x8*)(vp + 8);
        }
        __syncthreads();
        *(bf16x8*)(kbuf + c*LSTR + kh2)            = k0a;
        *(bf16x8*)(kbuf + c*LSTR + kh2 + 8)        = k0b;
        *(bf16x8*)(kbuf + KOFF + c*LSTR + kh2)     = k1a;
        *(bf16x8*)(kbuf + KOFF + c*LSTR + kh2 + 8) = k1b;
        if constexpr (PASS == 2) {
            *(bf16x8*)(vbuf + c*LSTR + kh2)     = va;
            *(bf16x8*)(vbuf + c*LSTR + kh2 + 8) = vb;
        }
        __syncthreads();

        f32x4 acc[2][4] = {};
        #pragma unroll
        for (int ks = 0; ks < 2; ++ks) {
            bf16x8 bH[4], bL[4];
            #pragma unroll
            for (int jj = 0; jj < 4; ++jj) {
                bH[jj] = *(const bf16x8*)(kbuf + (jj*16 + lrow)*LSTR + ks*32 + lq*8);
                bL[jj] = *(const bf16x8*)(kbuf + KOFF + (jj*16 + lrow)*LSTR + ks*32 + lq*8);
            }
            #pragma unroll
            for (int i = 0; i < 2; ++i)
                #pragma unroll
                for (int jj = 0; jj < 4; ++jj) {
                    acc[i][jj] = __builtin_amdgcn_mfma_f32_16x16x32_bf16(aH[i][ks], bH[jj], acc[i][jj], 0, 0, 0);
                    acc[i][jj] = __builtin_amdgcn_mfma_f32_16x16x32_bf16(aH[i][ks], bL[jj], acc[i][jj], 0, 0, 0);
                    acc[i][jj] = __builtin_amdgcn_mfma_f32_16x16x32_bf16(aL[i][ks], bH[jj], acc[i][jj], 0, 0, 0);
                }
        }

        #pragma unroll
        for (int i = 0; i < 2; ++i)
            #pragma unroll
            for (int rr = 0; rr < 4; ++rr) {
                if constexpr (PASS == 1) {
                    float s0 = acc[i][0][rr]*0.125f;
                    float s1 = acc[i][1][rr]*0.125f;
                    float s2 = acc[i][2][rr]*0.125f;
                    float s3 = acc[i][3][rr]*0.125f;
                    float tm = fmaxf(fmaxf(s0, s1), fmaxf(s2, s3));
                    float mo = m_st[i][rr];
                    float mn = fmaxf(mo, tm);
                    l_st[i][rr] = l_st[i][rr]*__expf(mo - mn)
                                + __expf(s0 - mn) + __expf(s1 - mn)
                                + __expf(s2 - mn) + __expf(s3 - mn);
                    m_st[i][rr] = mn;
                } else {
                    #pragma unroll
                    for (int jj = 0; jj < 4; ++jj) {
                        float p = __expf(acc[i][jj][rr]*0.125f - m_st[i][rr]) * l_st[i][rr];
                        qbuf[(w*32 + i*16 + lq*4 + rr)*LSTR + jj*16 + lrow] = f2bf(p);
                    }
                }
            }

        if constexpr (PASS == 2) {
            // wave-private: write the wave's 32x64 P tile to attn, coalesced
            // lane covers 4 consecutive cols; 16 lanes = 256B runs
            #pragma unroll
            for (int ri = 0; ri < 8; ++ri) {
                int rl = w*32 + ri*4 + lq;
                const short* src = qbuf + rl*LSTR + lrow*4;
                short4 p4 = *(const short4*)src;
                f32x4 f;
                f[0] = bf2f(p4.x); f[1] = bf2f(p4.y);
                f[2] = bf2f(p4.z); f[3] = bf2f(p4.w);
                __builtin_nontemporal_store(f,
                    (f32x4*)(attn + zbase + (size_t)(i0 + rl)*SQ + j0 + lrow*4));
            }
            // P*V (qbuf rows wave-private)
            #pragma unroll
            for (int ks = 0; ks < 2; ++ks) {
                bf16x8 ap[2], bv[4];
                #pragma unroll
                for (int i = 0; i < 2; ++i)
                    ap[i] = *(const bf16x8*)(qbuf + (w*32 + i*16 + lrow)*LSTR + ks*32 + lq*8);
                #pragma unroll
                for (int nd = 0; nd < 4; ++nd)
                    bv[nd] = *(const bf16x8*)(vbuf + (nd*16 + lrow)*LSTR + ks*32 + lq*8);
                #pragma unroll
                for (int i = 0; i < 2; ++i)
                    #pragma unroll
                    for (int nd = 0; nd < 4; ++nd)
                        oa[i][nd] = __builtin_amdgcn_mfma_f32_16x16x32_bf16(ap[i], bv[nd], oa[i][nd], 0, 0, 0);
            }
        }
    }

    if constexpr (PASS == 1) {
        #pragma unroll
        for (int i = 0; i < 2; ++i)
            #pragma unroll
            for (int rr = 0; rr < 4; ++rr) {
                float m = m_st[i][rr], lv = l_st[i][rr];
                #pragma unroll
                for (int off = 1; off < 16; off <<= 1) {
                    float m2 = __shfl_xor(m, off);
                    float l2 = __shfl_xor(lv, off);
                    float mn = fmaxf(m, m2);
                    lv = lv*__expf(m - mn) + l2*__expf(m2 - mn);
                    m = mn;
                }
                if (lrow == 0) {
                    int row = i0 + w*32 + i*16 + lq*4 + rr;
                    ml[(size_t)z*SQ + row] = m;
                    ml[(size_t)NB*NH*SQ + (size_t)z*SQ + row] = lv;
                }
            }
    } else {
        #pragma unroll
        for (int i = 0; i < 2; ++i)
            #pragma unroll
            for (int rr = 0; rr < 4; ++rr) {
                int row = i0 + w*32 + i*16 + lq*4 + rr;
                #pragma unroll
                for (int nd = 0; nd < 4; ++nd)
                    AO[(size_t)(b*SQ + row)*EMB + h*HD + nd*16 + lrow] = f2bf(oa[i][nd][rr]);
            }
    }
}

// ---------------------------------------------------------------------------
extern "C" void kernel_launch(void* const* d_in, const int* in_sizes, int n_in,
                              void* d_out, int out_size, void* d_ws, size_t ws_size,
                              hipStream_t stream)
{
    const float* hs   = (const float*)d_in[0];
    const int*   q_qw = (const int*)  d_in[1];
    const float* q_sc = (const float*)d_in[2];
    const float* q_zp = (const float*)d_in[3];
    const float* q_b  = (const float*)d_in[4];
    const int*   k_qw = (const int*)  d_in[5];
    const float* k_sc = (const float*)d_in[6];
    const float* k_zp = (const float*)d_in[7];
    const float* k_b  = (const float*)d_in[8];
    const int*   v_qw = (const int*)  d_in[9];
    const float* v_sc = (const float*)d_in[10];
    const float* v_zp = (const float*)d_in[11];
    const float* v_b  = (const float*)d_in[12];
    const int*   o_qw = (const int*)  d_in[13];
    const float* o_sc = (const float*)d_in[14];
    const float* o_zp = (const float*)d_in[15];
    const float* o_b  = (const float*)d_in[16];

    float* out  = (float*)d_out;
    float* attn = out + OUT0;

    // ws layout (60.5 MB <= 64 MB):
    //   ml | Wh: 4MW | Wl: 2MW (q,k) | Xh (->AO) | Xl (->Vt) | Qh | Ql | Kh | Kl
    const size_t WSZ = (size_t)EMB*EMB;
    const size_t TSZ = (size_t)BSQ*EMB;
    float* ml = (float*)d_ws;
    short* Wh = (short*)(ml + 2*(size_t)NB*NH*SQ);
    short* Wl = Wh + 4*WSZ;
    short* Xh = Wl + 2*WSZ;
    short* Xl = Xh + TSZ;
    short* Qh = Xl + TSZ;
    short* Ql = Qh + TSZ;
    short* Kh = Ql + TSZ;
    short* Kl = Kh + TSZ;
    short* Vt = Xl;   // overlay: Xl dead after K projection
    short* AO = Xh;   // overlay: Xh dead after V projection

    dim3 blk(256);

    k_prep<<<dim3(512, 1, 8), blk, 0, stream>>>(
        hs,
        q_qw, q_sc, q_zp, k_qw, k_sc, k_zp,
        v_qw, v_sc, v_zp, o_qw, o_sc, o_zp,
        Wh, Wl, Xh, Xl);

    k_projqkv<<<dim3(8, 32, 3), blk, 0, stream>>>(
        Xh, Xl, Wh, Wl, q_b, k_b, v_b, Qh, Ql, Kh, Kl, Vt);

    k_attn<1><<<dim3(16, 32), blk, 0, stream>>>(Qh, Ql, Kh, Kl, nullptr, ml, nullptr, nullptr);
    k_attn<2><<<dim3(16, 32), blk, 0, stream>>>(Qh, Ql, Kh, Kl, Vt, ml, attn, AO);

    k_projo<<<dim3(8, 32), blk, 0, stream>>>(AO, Wh + 3*WSZ, o_b, out);
}